// Round 3
// baseline (573.970 us; speedup 1.0000x reference)
//
#include <hip/hip_runtime.h>
#include <math.h>

typedef __attribute__((ext_vector_type(8))) short short8;
typedef __attribute__((ext_vector_type(4))) float f32x4;

__device__ __forceinline__ float b2f(short s) {
    unsigned u = ((unsigned)(unsigned short)s) << 16;
    return __builtin_bit_cast(float, u);
}
__device__ __forceinline__ short f2b(float f) {
    unsigned u = __builtin_bit_cast(unsigned, f);
    u += 0x7FFFu + ((u >> 16) & 1u);
    return (short)(u >> 16);
}

// ---------------- weight transpose + fp32->bf16: src (K x N fp32) -> dst (N x K bf16) ----
__global__ void transpose_w(const float* __restrict__ src, short* __restrict__ dst,
                            int K, int N) {
    int idx = blockIdx.x * 256 + threadIdx.x;
    if (idx < N * K) {
        int n = idx / K, k = idx - n * K;
        dst[idx] = f2b(src[(size_t)k * N + n]);
    }
}

// ---------------- LN1 + roll(-3) + window partition + gt concat ----------------
// out xc: (64*344) x 384 bf16, row r = w*344 + n ; n==0 -> gt[w], else LN(x[shifted pos])
__global__ __launch_bounds__(256) void ln1_window(
    const float* __restrict__ x, const float* __restrict__ gt,
    const float* __restrict__ g, const float* __restrict__ b,
    short* __restrict__ xc)
{
    int wid = threadIdx.x >> 6, lane = threadIdx.x & 63;
    int r = blockIdx.x * 4 + wid;
    int w = r / 344, n = r - w * 344;
    if (n == 0) {
        #pragma unroll
        for (int i = 0; i < 6; i++) {
            int c = lane + i * 64;
            xc[(size_t)r * 384 + c] = f2b(gt[(size_t)w * 384 + c]);
        }
        return;
    }
    int t = n - 1;
    int a = t / 49, rm = t - a * 49, bb = rm / 7, cc = rm - bb * 7;
    int hw = w >> 3, ww = w & 7;
    int s = (a < 4) ? a + 3 : a - 4;
    int h = hw * 7 + bb + 3; if (h >= 56) h -= 56;
    int wd = ww * 7 + cc + 3; if (wd >= 56) wd -= 56;
    const float* row = x + (size_t)((s * 56 + h) * 56 + wd) * 384;
    float v[6]; float sum = 0.f;
    #pragma unroll
    for (int i = 0; i < 6; i++) { v[i] = row[lane + i * 64]; sum += v[i]; }
    #pragma unroll
    for (int off = 32; off >= 1; off >>= 1) sum += __shfl_xor(sum, off);
    float mu = sum * (1.0f / 384.0f);
    float vs = 0.f;
    #pragma unroll
    for (int i = 0; i < 6; i++) { float d = v[i] - mu; vs += d * d; }
    #pragma unroll
    for (int off = 32; off >= 1; off >>= 1) vs += __shfl_xor(vs, off);
    float rstd = rsqrtf(vs * (1.0f / 384.0f) + 1e-5f);
    #pragma unroll
    for (int i = 0; i < 6; i++) {
        int c = lane + i * 64;
        float o = (v[i] - mu) * rstd * g[c] + b[c];
        xc[(size_t)r * 384 + c] = f2b(o);
    }
}

// ---------------- LN2 over fp32 x_new, token-major, out bf16 ----------------
__global__ __launch_bounds__(256) void ln2_kernel(
    const float* __restrict__ xn, const float* __restrict__ g,
    const float* __restrict__ b, short* __restrict__ out)
{
    int wid = threadIdx.x >> 6, lane = threadIdx.x & 63;
    int r = blockIdx.x * 4 + wid;          // token 0..21951
    const float* row = xn + (size_t)r * 384;
    float v[6]; float sum = 0.f;
    #pragma unroll
    for (int i = 0; i < 6; i++) { v[i] = row[lane + i * 64]; sum += v[i]; }
    #pragma unroll
    for (int off = 32; off >= 1; off >>= 1) sum += __shfl_xor(sum, off);
    float mu = sum * (1.0f / 384.0f);
    float vs = 0.f;
    #pragma unroll
    for (int i = 0; i < 6; i++) { float d = v[i] - mu; vs += d * d; }
    #pragma unroll
    for (int off = 32; off >= 1; off >>= 1) vs += __shfl_xor(vs, off);
    float rstd = rsqrtf(vs * (1.0f / 384.0f) + 1e-5f);
    #pragma unroll
    for (int i = 0; i < 6; i++) {
        int c = lane + i * 64;
        float o = (v[i] - mu) * rstd * g[c] + b[c];
        out[(size_t)r * 384 + c] = f2b(o);
    }
}

// ---------------- generic 64x64-tile bf16 MFMA GEMM ----------------
// A: M x K row-major (bf16), BT: N x K row-major (bf16), bias: [N] fp32
// EPI 0: out bf16 = acc + bias
// EPI 1: out bf16 = gelu(acc + bias)
// EPI 2: proj scatter: row->(w,n); n==0 -> P1 (gt out, FP32); else un-window+un-roll,
//        Out(float*)[td] = acc + bias + shortcut P0 (fp32 x)
// EPI 3: out FP32 = acc + bias + P0(fp32 x_new)[row*N+col]
template<int EPI>
__global__ __launch_bounds__(256) void gemm64(
    const short* __restrict__ A, const short* __restrict__ BT,
    const float* __restrict__ bias, void* __restrict__ Out,
    const void* __restrict__ P0, void* __restrict__ P1,
    int M, int N, int K)
{
    __shared__ short As[64 * 40];
    __shared__ short Bs[64 * 40];
    const int m0 = blockIdx.y * 64, n0 = blockIdx.x * 64;
    const int tid = threadIdx.x;
    const int lrow = tid >> 2, lchunk = tid & 3;
    const int wid = tid >> 6, lane = tid & 63;
    const int wm = wid >> 1, wn = wid & 1;
    const int l15 = lane & 15, quad = lane >> 4;
    f32x4 acc[2][2];
    #pragma unroll
    for (int i = 0; i < 2; i++)
        #pragma unroll
        for (int j = 0; j < 2; j++) acc[i][j] = (f32x4){0.f, 0.f, 0.f, 0.f};

    const short* Ap = A + (size_t)(m0 + lrow) * K + lchunk * 8;
    const short* Bp = BT + (size_t)(n0 + lrow) * K + lchunk * 8;

    for (int ks = 0; ks < K; ks += 32) {
        short8 av = *(const short8*)(Ap + ks);
        short8 bv = *(const short8*)(Bp + ks);
        __syncthreads();
        *(short8*)&As[lrow * 40 + lchunk * 8] = av;
        *(short8*)&Bs[lrow * 40 + lchunk * 8] = bv;
        __syncthreads();
        short8 a0 = *(const short8*)&As[(wm * 32 + l15) * 40 + quad * 8];
        short8 a1 = *(const short8*)&As[(wm * 32 + 16 + l15) * 40 + quad * 8];
        short8 b0 = *(const short8*)&Bs[(wn * 32 + l15) * 40 + quad * 8];
        short8 b1 = *(const short8*)&Bs[(wn * 32 + 16 + l15) * 40 + quad * 8];
        acc[0][0] = __builtin_amdgcn_mfma_f32_16x16x32_bf16(a0, b0, acc[0][0], 0, 0, 0);
        acc[0][1] = __builtin_amdgcn_mfma_f32_16x16x32_bf16(a0, b1, acc[0][1], 0, 0, 0);
        acc[1][0] = __builtin_amdgcn_mfma_f32_16x16x32_bf16(a1, b0, acc[1][0], 0, 0, 0);
        acc[1][1] = __builtin_amdgcn_mfma_f32_16x16x32_bf16(a1, b1, acc[1][1], 0, 0, 0);
    }

    #pragma unroll
    for (int mt = 0; mt < 2; mt++) {
        #pragma unroll
        for (int nt = 0; nt < 2; nt++) {
            #pragma unroll
            for (int r = 0; r < 4; r++) {
                int row = m0 + wm * 32 + mt * 16 + quad * 4 + r;
                int col = n0 + wn * 32 + nt * 16 + l15;
                float v = acc[mt][nt][r] + bias[col];
                if (EPI == 0) {
                    ((short*)Out)[(size_t)row * N + col] = f2b(v);
                } else if (EPI == 1) {
                    v = 0.5f * v * (1.0f + erff(v * 0.7071067811865476f));
                    ((short*)Out)[(size_t)row * N + col] = f2b(v);
                } else if (EPI == 2) {
                    int w = row / 344, n = row - w * 344;
                    if (n == 0) {
                        ((float*)P1)[(size_t)w * 384 + col] = v;
                    } else {
                        int t = n - 1;
                        int a = t / 49, rm = t - a * 49;
                        int bb = rm / 7, cc = rm - bb * 7;
                        int hw = w >> 3, ww = w & 7;
                        int s = (a < 4) ? a + 3 : a - 4;
                        int h = hw * 7 + bb + 3; if (h >= 56) h -= 56;
                        int wd = ww * 7 + cc + 3; if (wd >= 56) wd -= 56;
                        size_t td = (size_t)((s * 56 + h) * 56 + wd) * 384 + col;
                        ((float*)Out)[td] = v + ((const float*)P0)[td];
                    }
                } else {  // EPI 3
                    v += ((const float*)P0)[(size_t)row * N + col];
                    ((float*)Out)[(size_t)row * N + col] = v;
                }
            }
        }
    }
}

// ---------------- fused windowed attention ----------------
// one block per (window, head): QK^T (MFMA, direct global frags) + bias + mask
// + softmax + PV (MFMA, P via LDS chunk round-trip, V transposed in LDS)
__global__ __launch_bounds__(256) void attn_kernel(
    const short* __restrict__ qkv, const float* __restrict__ bias_table,
    short* __restrict__ attn_out)
{
    __shared__ short VT[32 * 360];       // V^T: [dd][key], stride 360
    __shared__ short Pbuf[4 * 16 * 40];  // per-wave P chunk: 16 rows x 32 (stride 40)
    const int blk = blockIdx.x;
    const int w = blk / 12, head = blk - w * 12;
    const int tid = threadIdx.x;
    const int wid = tid >> 6, lane = tid & 63;
    const int l15 = lane & 15, quad = lane >> 4;
    const size_t base = (size_t)w * 344 * 1152 + head * 32;

    for (int e = tid; e < 344 * 32; e += 256) {
        int key = e >> 5, dd = e & 31;
        VT[dd * 360 + key] = qkv[base + 768 + (size_t)key * 1152 + dd];
    }
    for (int e = tid; e < 16 * 32; e += 256) {
        int key = 344 + (e >> 5), dd = e & 31;
        VT[dd * 360 + key] = 0;
    }
    __syncthreads();

    const int hw = w >> 3, ww = w & 7;
    // per-lane column info for each of 22 key tiles (col j = nb*16 + l15)
    int cja[22], cjb[22], cjc[22], cjid[22];
    #pragma unroll
    for (int nb = 0; nb < 22; nb++) {
        int j = nb * 16 + l15;
        int t = j - 1;
        int a = t / 49, rm = t - a * 49;
        int bb = rm / 7, cc = rm - bb * 7;
        cja[nb] = a; cjb[nb] = bb; cjc[nb] = cc;
        int h = hw * 7 + bb, wd = ww * 7 + cc;
        int gs = (a < 4) ? 1 : 2;
        int gh = (h < 49) ? 0 : ((h < 53) ? 1 : 2);
        int gw = (wd < 49) ? 0 : ((wd < 53) ? 1 : 2);
        cjid[nb] = gs * 9 + gh * 3 + gw;
    }

    const float scale = 0.17677669529663687f;  // 32^-0.5

    for (int rt = wid; rt < 22; rt += 4) {
        int mbase = rt * 16;
        int qr = mbase + l15; if (qr > 343) qr = 343;
        short8 af = *(const short8*)&qkv[base + (size_t)qr * 1152 + quad * 8];

        f32x4 sc[22];
        #pragma unroll
        for (int nb = 0; nb < 22; nb++) {
            int kr = nb * 16 + l15; if (kr > 343) kr = 343;
            short8 bfr = *(const short8*)&qkv[base + 384 + (size_t)kr * 1152 + quad * 8];
            f32x4 z = {0.f, 0.f, 0.f, 0.f};
            sc[nb] = __builtin_amdgcn_mfma_f32_16x16x32_bf16(af, bfr, z, 0, 0, 0);
        }

        // per-lane row info (rows mbase + quad*4 + r)
        int ria[4], rib[4], ric[4], riid[4];
        #pragma unroll
        for (int r = 0; r < 4; r++) {
            int i = mbase + quad * 4 + r;
            int t = i - 1;
            int a = t / 49, rm = t - a * 49;
            int bb = rm / 7, cc = rm - bb * 7;
            ria[r] = a; rib[r] = bb; ric[r] = cc;
            int h = hw * 7 + bb, wd = ww * 7 + cc;
            int gs = (a < 4) ? 1 : 2;
            int gh = (h < 49) ? 0 : ((h < 53) ? 1 : 2);
            int gw = (wd < 49) ? 0 : ((wd < 53) ? 1 : 2);
            riid[r] = gs * 9 + gh * 3 + gw;
        }

        // scale + rel-pos bias + shift mask + padding
        #pragma unroll
        for (int nb = 0; nb < 22; nb++) {
            int j = nb * 16 + l15;
            #pragma unroll
            for (int r = 0; r < 4; r++) {
                int i = mbase + quad * 4 + r;
                float s = sc[nb][r] * scale;
                if (j >= 344) {
                    s = -1e30f;
                } else if (j > 0 && i > 0) {
                    int idx = (ria[r] - cja[nb] + 6) * 20 + (rib[r] - cjb[nb] + 6) * 13
                              + (ric[r] - cjc[nb] + 6);
                    s += bias_table[idx * 12 + head];
                    if (riid[r] != cjid[nb]) s -= 100.0f;
                }
                sc[nb][r] = s;
            }
        }

        // softmax over 352 cols (16 lanes of the quad hold each row)
        float mx[4] = {-1e30f, -1e30f, -1e30f, -1e30f};
        #pragma unroll
        for (int nb = 0; nb < 22; nb++)
            #pragma unroll
            for (int r = 0; r < 4; r++) mx[r] = fmaxf(mx[r], sc[nb][r]);
        #pragma unroll
        for (int r = 0; r < 4; r++) {
            mx[r] = fmaxf(mx[r], __shfl_xor(mx[r], 1));
            mx[r] = fmaxf(mx[r], __shfl_xor(mx[r], 2));
            mx[r] = fmaxf(mx[r], __shfl_xor(mx[r], 4));
            mx[r] = fmaxf(mx[r], __shfl_xor(mx[r], 8));
        }
        float sm[4] = {0.f, 0.f, 0.f, 0.f};
        #pragma unroll
        for (int nb = 0; nb < 22; nb++)
            #pragma unroll
            for (int r = 0; r < 4; r++) {
                float p = __expf(sc[nb][r] - mx[r]);
                sc[nb][r] = p; sm[r] += p;
            }
        #pragma unroll
        for (int r = 0; r < 4; r++) {
            sm[r] += __shfl_xor(sm[r], 1);
            sm[r] += __shfl_xor(sm[r], 2);
            sm[r] += __shfl_xor(sm[r], 4);
            sm[r] += __shfl_xor(sm[r], 8);
        }
        float inv[4];
        #pragma unroll
        for (int r = 0; r < 4; r++) inv[r] = 1.0f / sm[r];

        // PV: chunk 32 keys at a time through LDS (C-layout -> A-layout)
        f32x4 o0 = {0.f, 0.f, 0.f, 0.f}, o1 = {0.f, 0.f, 0.f, 0.f};
        short* Pw = &Pbuf[wid * 16 * 40];
        #pragma unroll
        for (int kk = 0; kk < 11; kk++) {
            #pragma unroll
            for (int hh = 0; hh < 2; hh++) {
                int nb = kk * 2 + hh;
                #pragma unroll
                for (int r = 0; r < 4; r++)
                    Pw[(quad * 4 + r) * 40 + hh * 16 + l15] = f2b(sc[nb][r] * inv[r]);
            }
            short8 pa  = *(const short8*)&Pw[l15 * 40 + quad * 8];
            short8 vb0 = *(const short8*)&VT[l15 * 360 + kk * 32 + quad * 8];
            short8 vb1 = *(const short8*)&VT[(16 + l15) * 360 + kk * 32 + quad * 8];
            o0 = __builtin_amdgcn_mfma_f32_16x16x32_bf16(pa, vb0, o0, 0, 0, 0);
            o1 = __builtin_amdgcn_mfma_f32_16x16x32_bf16(pa, vb1, o1, 0, 0, 0);
        }

        #pragma unroll
        for (int r = 0; r < 4; r++) {
            int row = mbase + quad * 4 + r;
            if (row < 344) {
                size_t ob = ((size_t)w * 344 + row) * 384 + head * 32;
                attn_out[ob + l15] = f2b(o0[r]);
                attn_out[ob + 16 + l15] = f2b(o1[r]);
            }
        }
    }
}

extern "C" void kernel_launch(void* const* d_in, const int* in_sizes, int n_in,
                              void* d_out, int out_size, void* d_ws, size_t ws_size,
                              hipStream_t stream)
{
    const float* x      = (const float*)d_in[0];
    const float* gt     = (const float*)d_in[1];
    const float* n1g    = (const float*)d_in[2];
    const float* n1b    = (const float*)d_in[3];
    const float* qkv_w  = (const float*)d_in[4];
    const float* qkv_b  = (const float*)d_in[5];
    const float* btab   = (const float*)d_in[6];
    const float* proj_w = (const float*)d_in[7];
    const float* proj_b = (const float*)d_in[8];
    const float* n2g    = (const float*)d_in[9];
    const float* n2b    = (const float*)d_in[10];
    const float* fc1_w  = (const float*)d_in[11];
    const float* fc1_b  = (const float*)d_in[12];
    const float* fc2_w  = (const float*)d_in[13];
    const float* fc2_b  = (const float*)d_in[14];

    char* ws = (char*)d_ws;
    short* wt_qkv  = (short*)(ws + 0);          //  1152x384 bf16
    short* wt_proj = (short*)(ws + 884736);     //   384x384 bf16
    short* wt_fc1  = (short*)(ws + 1179648);    //  1536x384 bf16
    short* wt_fc2  = (short*)(ws + 2359296);    //   384x1536 bf16
    short* xc      = (short*)(ws + 3538944);    // 22016x384 bf16
    short* qkvb    = (short*)(ws + 20447232);   // 22016x1152 bf16
    short* attn_o  = xc;                        // reuse (xc dead after qkv GEMM)
    short* h1      = (short*)(ws + 3538944);    // 21952x1536 bf16 (reuse xc region)
    float* xnew    = (float*)(ws + 71172096);   // 21952x384 fp32
    short* xnorm   = (short*)(ws + 104890368);  // 21952x384 bf16

    float* outx  = (float*)d_out;
    float* outgt = outx + (size_t)21952 * 384;

    transpose_w<<<dim3((442368 + 255) / 256), 256, 0, stream>>>(qkv_w, wt_qkv, 384, 1152);
    transpose_w<<<dim3((147456 + 255) / 256), 256, 0, stream>>>(proj_w, wt_proj, 384, 384);
    transpose_w<<<dim3((589824 + 255) / 256), 256, 0, stream>>>(fc1_w, wt_fc1, 384, 1536);
    transpose_w<<<dim3((589824 + 255) / 256), 256, 0, stream>>>(fc2_w, wt_fc2, 1536, 384);

    ln1_window<<<dim3(5504), 256, 0, stream>>>(x, gt, n1g, n1b, xc);

    gemm64<0><<<dim3(18, 344), 256, 0, stream>>>(xc, wt_qkv, qkv_b, qkvb,
                                                 nullptr, nullptr, 22016, 1152, 384);

    attn_kernel<<<dim3(768), 256, 0, stream>>>(qkvb, btab, attn_o);

    gemm64<2><<<dim3(6, 344), 256, 0, stream>>>(attn_o, wt_proj, proj_b, xnew,
                                                x, outgt, 22016, 384, 384);

    ln2_kernel<<<dim3(5488), 256, 0, stream>>>(xnew, n2g, n2b, xnorm);

    gemm64<1><<<dim3(24, 343), 256, 0, stream>>>(xnorm, wt_fc1, fc1_b, h1,
                                                 nullptr, nullptr, 21952, 1536, 384);

    gemm64<3><<<dim3(6, 343), 256, 0, stream>>>(h1, wt_fc2, fc2_b, outx,
                                                xnew, nullptr, 21952, 384, 1536);
}

// Round 5
// 531.546 us; speedup vs baseline: 1.0798x; 1.0798x over previous
//
#include <hip/hip_runtime.h>
#include <math.h>

typedef __attribute__((ext_vector_type(8))) short short8;
typedef __attribute__((ext_vector_type(4))) float f32x4;

__device__ __forceinline__ float b2f(short s) {
    unsigned u = ((unsigned)(unsigned short)s) << 16;
    return __builtin_bit_cast(float, u);
}
__device__ __forceinline__ short f2b(float f) {
    unsigned u = __builtin_bit_cast(unsigned, f);
    u += 0x7FFFu + ((u >> 16) & 1u);
    return (short)(u >> 16);
}

// ---------------- weight transpose + fp32->bf16: src (K x N fp32) -> dst (N x K bf16) ----
__global__ void transpose_w(const float* __restrict__ src, short* __restrict__ dst,
                            int K, int N) {
    int idx = blockIdx.x * 256 + threadIdx.x;
    if (idx < N * K) {
        int n = idx / K, k = idx - n * K;
        dst[idx] = f2b(src[(size_t)k * N + n]);
    }
}

// ---------------- precompute padded rel-pos bias: btot[12][352][352] fp32 ----------------
__global__ void bias_pre(const float* __restrict__ btab, float* __restrict__ btot) {
    int idx = blockIdx.x * 256 + threadIdx.x;
    if (idx >= 12 * 352 * 352) return;
    int head = idx / (352 * 352), rem = idx % (352 * 352);
    int i = rem / 352, j = rem % 352;
    float v = 0.f;
    if (i > 0 && i < 344 && j > 0 && j < 344) {
        int ti = i - 1, tj = j - 1;
        int ai = ti / 49, bi = (ti % 49) / 7, ci = ti % 7;
        int aj = tj / 49, bj = (tj % 49) / 7, cj = tj % 7;
        int id3 = (ai - aj + 6) * 20 + (bi - bj + 6) * 13 + (ci - cj + 6);
        v = btab[id3 * 12 + head];
    }
    btot[idx] = v;
}

// ---------------- precompute shift-mask group ids: gid[64][352] uint8 ----------------
__global__ void gid_pre(unsigned char* __restrict__ gid) {
    int idx = blockIdx.x * 256 + threadIdx.x;
    if (idx >= 64 * 352) return;
    int w = idx / 352, n = idx % 352;
    unsigned char g = 0;
    if (n >= 1 && n < 344) {
        int t = n - 1;
        int a = t / 49, bb = (t % 49) / 7, cc = t % 7;
        int hw = w >> 3, ww = w & 7;
        int h = hw * 7 + bb, wd = ww * 7 + cc;
        int gs = (a < 4) ? 1 : 2;
        int gh = (h < 49) ? 0 : ((h < 53) ? 1 : 2);
        int gw = (wd < 49) ? 0 : ((wd < 53) ? 1 : 2);
        g = (unsigned char)(gs * 9 + gh * 3 + gw);
    }
    gid[idx] = g;
}

// ---------------- LN1 + roll(-3) + window partition + gt concat ----------------
__global__ __launch_bounds__(256) void ln1_window(
    const float* __restrict__ x, const float* __restrict__ gt,
    const float* __restrict__ g, const float* __restrict__ b,
    short* __restrict__ xc)
{
    int wid = threadIdx.x >> 6, lane = threadIdx.x & 63;
    int r = blockIdx.x * 4 + wid;
    int w = r / 344, n = r - w * 344;
    if (n == 0) {
        #pragma unroll
        for (int i = 0; i < 6; i++) {
            int c = lane + i * 64;
            xc[(size_t)r * 384 + c] = f2b(gt[(size_t)w * 384 + c]);
        }
        return;
    }
    int t = n - 1;
    int a = t / 49, rm = t - a * 49, bb = rm / 7, cc = rm - bb * 7;
    int hw = w >> 3, ww = w & 7;
    int s = (a < 4) ? a + 3 : a - 4;
    int h = hw * 7 + bb + 3; if (h >= 56) h -= 56;
    int wd = ww * 7 + cc + 3; if (wd >= 56) wd -= 56;
    const float* row = x + (size_t)((s * 56 + h) * 56 + wd) * 384;
    float v[6]; float sum = 0.f;
    #pragma unroll
    for (int i = 0; i < 6; i++) { v[i] = row[lane + i * 64]; sum += v[i]; }
    #pragma unroll
    for (int off = 32; off >= 1; off >>= 1) sum += __shfl_xor(sum, off);
    float mu = sum * (1.0f / 384.0f);
    float vs = 0.f;
    #pragma unroll
    for (int i = 0; i < 6; i++) { float d = v[i] - mu; vs += d * d; }
    #pragma unroll
    for (int off = 32; off >= 1; off >>= 1) vs += __shfl_xor(vs, off);
    float rstd = rsqrtf(vs * (1.0f / 384.0f) + 1e-5f);
    #pragma unroll
    for (int i = 0; i < 6; i++) {
        int c = lane + i * 64;
        float o = (v[i] - mu) * rstd * g[c] + b[c];
        xc[(size_t)r * 384 + c] = f2b(o);
    }
}

// ---------------- LN2 over fp32 x_new, token-major, out bf16 ----------------
__global__ __launch_bounds__(256) void ln2_kernel(
    const float* __restrict__ xn, const float* __restrict__ g,
    const float* __restrict__ b, short* __restrict__ out)
{
    int wid = threadIdx.x >> 6, lane = threadIdx.x & 63;
    int r = blockIdx.x * 4 + wid;
    const float* row = xn + (size_t)r * 384;
    float v[6]; float sum = 0.f;
    #pragma unroll
    for (int i = 0; i < 6; i++) { v[i] = row[lane + i * 64]; sum += v[i]; }
    #pragma unroll
    for (int off = 32; off >= 1; off >>= 1) sum += __shfl_xor(sum, off);
    float mu = sum * (1.0f / 384.0f);
    float vs = 0.f;
    #pragma unroll
    for (int i = 0; i < 6; i++) { float d = v[i] - mu; vs += d * d; }
    #pragma unroll
    for (int off = 32; off >= 1; off >>= 1) vs += __shfl_xor(vs, off);
    float rstd = rsqrtf(vs * (1.0f / 384.0f) + 1e-5f);
    #pragma unroll
    for (int i = 0; i < 6; i++) {
        int c = lane + i * 64;
        float o = (v[i] - mu) * rstd * g[c] + b[c];
        out[(size_t)r * 384 + c] = f2b(o);
    }
}

// ---------------- 128x128-tile bf16 MFMA GEMM (m93-style, 4 waves, 4x4 MFMA/wave) ------
template<int EPI>
__global__ __launch_bounds__(256) void gemm128(
    const short* __restrict__ A, const short* __restrict__ BT,
    const float* __restrict__ bias, void* __restrict__ Out,
    const void* __restrict__ P0, void* __restrict__ P1,
    int M, int N, int K)
{
    __shared__ short As[128 * 40];
    __shared__ short Bs[128 * 40];
    const int m0 = blockIdx.y * 128, n0 = blockIdx.x * 128;
    const int tid = threadIdx.x;
    const int wid = tid >> 6, lane = tid & 63;
    const int wm = wid >> 1, wn = wid & 1;
    const int l15 = lane & 15, quad = lane >> 4;
    const int srow0 = tid >> 2, scol = (tid & 3) * 8;
    const int srow1 = 64 + srow0;

    f32x4 acc[4][4];
    #pragma unroll
    for (int i = 0; i < 4; i++)
        #pragma unroll
        for (int j = 0; j < 4; j++) acc[i][j] = (f32x4){0.f, 0.f, 0.f, 0.f};

    int ar0 = m0 + srow0; if (ar0 >= M) ar0 = M - 1;
    int ar1 = m0 + srow1; if (ar1 >= M) ar1 = M - 1;
    const short* Ap0 = A + (size_t)ar0 * K + scol;
    const short* Ap1 = A + (size_t)ar1 * K + scol;
    const short* Bp0 = BT + (size_t)(n0 + srow0) * K + scol;
    const short* Bp1 = BT + (size_t)(n0 + srow1) * K + scol;

    for (int ks = 0; ks < K; ks += 32) {
        short8 a0 = *(const short8*)(Ap0 + ks);
        short8 a1 = *(const short8*)(Ap1 + ks);
        short8 b0 = *(const short8*)(Bp0 + ks);
        short8 b1 = *(const short8*)(Bp1 + ks);
        __syncthreads();
        *(short8*)&As[srow0 * 40 + scol] = a0;
        *(short8*)&As[srow1 * 40 + scol] = a1;
        *(short8*)&Bs[srow0 * 40 + scol] = b0;
        *(short8*)&Bs[srow1 * 40 + scol] = b1;
        __syncthreads();
        short8 af[4], bf[4];
        #pragma unroll
        for (int mt = 0; mt < 4; mt++)
            af[mt] = *(const short8*)&As[(wm * 64 + mt * 16 + l15) * 40 + quad * 8];
        #pragma unroll
        for (int nt = 0; nt < 4; nt++)
            bf[nt] = *(const short8*)&Bs[(wn * 64 + nt * 16 + l15) * 40 + quad * 8];
        #pragma unroll
        for (int mt = 0; mt < 4; mt++)
            #pragma unroll
            for (int nt = 0; nt < 4; nt++)
                acc[mt][nt] = __builtin_amdgcn_mfma_f32_16x16x32_bf16(af[mt], bf[nt],
                                                                      acc[mt][nt], 0, 0, 0);
    }

    #pragma unroll
    for (int mt = 0; mt < 4; mt++) {
        #pragma unroll
        for (int nt = 0; nt < 4; nt++) {
            #pragma unroll
            for (int r = 0; r < 4; r++) {
                int row = m0 + wm * 64 + mt * 16 + quad * 4 + r;
                int col = n0 + wn * 64 + nt * 16 + l15;
                if (row >= M) continue;
                float v = acc[mt][nt][r] + bias[col];
                if (EPI == 0) {
                    ((short*)Out)[(size_t)row * N + col] = f2b(v);
                } else if (EPI == 1) {
                    v = 0.5f * v * (1.0f + erff(v * 0.7071067811865476f));
                    ((short*)Out)[(size_t)row * N + col] = f2b(v);
                } else if (EPI == 2) {
                    int w = row / 344, n = row - w * 344;
                    if (n == 0) {
                        ((float*)P1)[(size_t)w * 384 + col] = v;
                    } else {
                        int t = n - 1;
                        int a = t / 49, rm = t - a * 49;
                        int bb = rm / 7, cc = rm - bb * 7;
                        int hw = w >> 3, ww = w & 7;
                        int s = (a < 4) ? a + 3 : a - 4;
                        int h = hw * 7 + bb + 3; if (h >= 56) h -= 56;
                        int wd = ww * 7 + cc + 3; if (wd >= 56) wd -= 56;
                        size_t td = (size_t)((s * 56 + h) * 56 + wd) * 384 + col;
                        ((float*)Out)[td] = v + ((const float*)P0)[td];
                    }
                } else {  // EPI 3
                    v += ((const float*)P0)[(size_t)row * N + col];
                    ((float*)Out)[(size_t)row * N + col] = v;
                }
            }
        }
    }
}

// ---------------- fused windowed attention ----------------
__global__ __launch_bounds__(256) void attn_kernel(
    const short* __restrict__ qkv, const float* __restrict__ btot,
    const unsigned char* __restrict__ gid, short* __restrict__ attn_out)
{
    __shared__ short VT[32 * 360];        // V^T: [dd][key], stride 360
    __shared__ short Pbuf[4 * 16 * 40];   // per-wave P chunk
    __shared__ unsigned char Gs[352];     // group ids for this window
    const int blk = blockIdx.x;
    const int w = blk / 12, head = blk - w * 12;
    const int tid = threadIdx.x;
    const int wid = tid >> 6, lane = tid & 63;
    const int l15 = lane & 15, quad = lane >> 4;
    const size_t base = (size_t)w * 344 * 1152 + head * 32;

    for (int e = tid; e < 344 * 32; e += 256) {
        int key = e >> 5, dd = e & 31;
        VT[dd * 360 + key] = qkv[base + 768 + (size_t)key * 1152 + dd];
    }
    for (int e = tid; e < 16 * 32; e += 256) {
        int key = 344 + (e >> 5), dd = e & 31;
        VT[dd * 360 + key] = 0;
    }
    for (int e = tid; e < 352; e += 256) Gs[e] = gid[w * 352 + e];   // FIX: full 352 staged
    __syncthreads();

    const float scale = 0.17677669529663687f;  // 32^-0.5
    const float* bhead = btot + (size_t)head * 352 * 352;

    for (int rt = wid; rt < 22; rt += 4) {
        int mbase = rt * 16;
        int qr = mbase + l15; if (qr > 343) qr = 343;
        short8 af = *(const short8*)&qkv[base + (size_t)qr * 1152 + quad * 8];

        f32x4 sc[22];
        #pragma unroll
        for (int nb = 0; nb < 22; nb++) {
            int kr = nb * 16 + l15; if (kr > 343) kr = 343;
            short8 bfr = *(const short8*)&qkv[base + 384 + (size_t)kr * 1152 + quad * 8];
            f32x4 z = {0.f, 0.f, 0.f, 0.f};
            sc[nb] = __builtin_amdgcn_mfma_f32_16x16x32_bf16(af, bfr, z, 0, 0, 0);
        }

        const float* bp[4];
        int rg[4];
        #pragma unroll
        for (int r = 0; r < 4; r++) {
            int i = mbase + quad * 4 + r;            // <= 351
            bp[r] = bhead + (size_t)i * 352 + l15;
            rg[r] = Gs[i];
        }

        #pragma unroll
        for (int nb = 0; nb < 22; nb++) {
            int j = nb * 16 + l15;
            int cg = Gs[j];
            bool jpos = (nb > 0) | (l15 > 0);
            #pragma unroll
            for (int r = 0; r < 4; r++) {
                int i = mbase + quad * 4 + r;
                float s = sc[nb][r] * scale + bp[r][nb * 16];
                if (jpos && i > 0 && rg[r] != cg) s -= 100.0f;
                if (j >= 344) s = -1e30f;
                sc[nb][r] = s;
            }
        }

        // softmax (16-lane groups hold each row)
        float mx[4] = {-1e30f, -1e30f, -1e30f, -1e30f};
        #pragma unroll
        for (int nb = 0; nb < 22; nb++)
            #pragma unroll
            for (int r = 0; r < 4; r++) mx[r] = fmaxf(mx[r], sc[nb][r]);
        #pragma unroll
        for (int r = 0; r < 4; r++) {
            mx[r] = fmaxf(mx[r], __shfl_xor(mx[r], 1));
            mx[r] = fmaxf(mx[r], __shfl_xor(mx[r], 2));
            mx[r] = fmaxf(mx[r], __shfl_xor(mx[r], 4));
            mx[r] = fmaxf(mx[r], __shfl_xor(mx[r], 8));
        }
        float sm[4] = {0.f, 0.f, 0.f, 0.f};
        #pragma unroll
        for (int nb = 0; nb < 22; nb++)
            #pragma unroll
            for (int r = 0; r < 4; r++) {
                float p = __expf(sc[nb][r] - mx[r]);
                sc[nb][r] = p; sm[r] += p;
            }
        #pragma unroll
        for (int r = 0; r < 4; r++) {
            sm[r] += __shfl_xor(sm[r], 1);
            sm[r] += __shfl_xor(sm[r], 2);
            sm[r] += __shfl_xor(sm[r], 4);
            sm[r] += __shfl_xor(sm[r], 8);
        }
        float inv[4];
        #pragma unroll
        for (int r = 0; r < 4; r++) inv[r] = 1.0f / sm[r];

        // PV via LDS chunk round-trip
        f32x4 o0 = {0.f, 0.f, 0.f, 0.f}, o1 = {0.f, 0.f, 0.f, 0.f};
        short* Pw = &Pbuf[wid * 16 * 40];
        #pragma unroll
        for (int kk = 0; kk < 11; kk++) {
            #pragma unroll
            for (int hh = 0; hh < 2; hh++) {
                int nb = kk * 2 + hh;
                #pragma unroll
                for (int r = 0; r < 4; r++)
                    Pw[(quad * 4 + r) * 40 + hh * 16 + l15] = f2b(sc[nb][r] * inv[r]);
            }
            short8 pa  = *(const short8*)&Pw[l15 * 40 + quad * 8];
            short8 vb0 = *(const short8*)&VT[l15 * 360 + kk * 32 + quad * 8];
            short8 vb1 = *(const short8*)&VT[(16 + l15) * 360 + kk * 32 + quad * 8];
            o0 = __builtin_amdgcn_mfma_f32_16x16x32_bf16(pa, vb0, o0, 0, 0, 0);
            o1 = __builtin_amdgcn_mfma_f32_16x16x32_bf16(pa, vb1, o1, 0, 0, 0);
        }

        #pragma unroll
        for (int r = 0; r < 4; r++) {
            int row = mbase + quad * 4 + r;
            if (row < 344) {
                size_t ob = ((size_t)w * 344 + row) * 384 + head * 32;
                attn_out[ob + l15] = f2b(o0[r]);
                attn_out[ob + 16 + l15] = f2b(o1[r]);
            }
        }
    }
}

extern "C" void kernel_launch(void* const* d_in, const int* in_sizes, int n_in,
                              void* d_out, int out_size, void* d_ws, size_t ws_size,
                              hipStream_t stream)
{
    const float* x      = (const float*)d_in[0];
    const float* gt     = (const float*)d_in[1];
    const float* n1g    = (const float*)d_in[2];
    const float* n1b    = (const float*)d_in[3];
    const float* qkv_w  = (const float*)d_in[4];
    const float* qkv_b  = (const float*)d_in[5];
    const float* btab   = (const float*)d_in[6];
    const float* proj_w = (const float*)d_in[7];
    const float* proj_b = (const float*)d_in[8];
    const float* n2g    = (const float*)d_in[9];
    const float* n2b    = (const float*)d_in[10];
    const float* fc1_w  = (const float*)d_in[11];
    const float* fc1_b  = (const float*)d_in[12];
    const float* fc2_w  = (const float*)d_in[13];
    const float* fc2_b  = (const float*)d_in[14];

    char* ws = (char*)d_ws;
    short* wt_qkv  = (short*)(ws + 0);          //  1152x384 bf16
    short* wt_proj = (short*)(ws + 884736);     //   384x384 bf16
    short* wt_fc1  = (short*)(ws + 1179648);    //  1536x384 bf16
    short* wt_fc2  = (short*)(ws + 2359296);    //   384x1536 bf16
    short* xc      = (short*)(ws + 3538944);    // 22016x384 bf16
    short* qkvb    = (short*)(ws + 20447232);   // 22016x1152 bf16
    short* attn_o  = xc;                        // reuse (xc dead after qkv GEMM)
    short* h1      = (short*)(ws + 3538944);    // 21952x1536 bf16 (reuse xc region)
    float* xnew    = (float*)(ws + 71172096);   // 21952x384 fp32
    float* btot    = (float*)(ws + 71172096);   // 12x352x352 fp32 (dead before xnew written)
    unsigned char* gidb = (unsigned char*)(ws + 77119488);  // 64x352 u8
    short* xnorm   = (short*)(ws + 104890368);  // 21952x384 bf16

    float* outx  = (float*)d_out;
    float* outgt = outx + (size_t)21952 * 384;

    transpose_w<<<dim3((442368 + 255) / 256), 256, 0, stream>>>(qkv_w, wt_qkv, 384, 1152);
    transpose_w<<<dim3((147456 + 255) / 256), 256, 0, stream>>>(proj_w, wt_proj, 384, 384);
    transpose_w<<<dim3((589824 + 255) / 256), 256, 0, stream>>>(fc1_w, wt_fc1, 384, 1536);
    transpose_w<<<dim3((589824 + 255) / 256), 256, 0, stream>>>(fc2_w, wt_fc2, 1536, 384);

    bias_pre<<<dim3((12 * 352 * 352 + 255) / 256), 256, 0, stream>>>(btab, btot);
    gid_pre<<<dim3((64 * 352 + 255) / 256), 256, 0, stream>>>(gidb);

    ln1_window<<<dim3(5504), 256, 0, stream>>>(x, gt, n1g, n1b, xc);

    gemm128<0><<<dim3(9, 172), 256, 0, stream>>>(xc, wt_qkv, qkv_b, qkvb,
                                                 nullptr, nullptr, 22016, 1152, 384);

    attn_kernel<<<dim3(768), 256, 0, stream>>>(qkvb, btot, gidb, attn_o);

    gemm128<2><<<dim3(3, 172), 256, 0, stream>>>(attn_o, wt_proj, proj_b, xnew,
                                                 x, outgt, 22016, 384, 384);

    ln2_kernel<<<dim3(5488), 256, 0, stream>>>(xnew, n2g, n2b, xnorm);

    gemm128<1><<<dim3(12, 172), 256, 0, stream>>>(xnorm, wt_fc1, fc1_b, h1,
                                                  nullptr, nullptr, 21952, 1536, 384);

    gemm128<3><<<dim3(3, 172), 256, 0, stream>>>(h1, wt_fc2, fc2_b, outx,
                                                 xnew, nullptr, 21952, 384, 1536);
}

// Round 6
// 517.121 us; speedup vs baseline: 1.1099x; 1.0279x over previous
//
#include <hip/hip_runtime.h>
#include <math.h>

typedef __attribute__((ext_vector_type(8))) short short8;
typedef __attribute__((ext_vector_type(4))) float f32x4;

__device__ __forceinline__ float b2f(short s) {
    unsigned u = ((unsigned)(unsigned short)s) << 16;
    return __builtin_bit_cast(float, u);
}
__device__ __forceinline__ short f2b(float f) {
    unsigned u = __builtin_bit_cast(unsigned, f);
    u += 0x7FFFu + ((u >> 16) & 1u);
    return (short)(u >> 16);
}
// async global->LDS, 16B per lane; lds base must be wave-uniform
__device__ __forceinline__ void gload16(const void* g, void* l) {
    __builtin_amdgcn_global_load_lds(
        (const __attribute__((address_space(1))) unsigned int*)g,
        (__attribute__((address_space(3))) unsigned int*)l, 16, 0, 0);
}

// ---------------- weight transpose + fp32->bf16: src (K x N fp32) -> dst (N x K bf16) ----
__global__ void transpose_w(const float* __restrict__ src, short* __restrict__ dst,
                            int K, int N) {
    int idx = blockIdx.x * 256 + threadIdx.x;
    if (idx < N * K) {
        int n = idx / K, k = idx - n * K;
        dst[idx] = f2b(src[(size_t)k * N + n]);
    }
}

// ------- precompute rel-pos bias in MFMA C-fragment layout: btf[12][22][22][64][4] -------
// value at (head, i=rt*16+(lane>>4)*4+r, j=nb*16+(lane&15)); j>=344 -> -1e30 (padding)
__global__ void bias_pre(const float* __restrict__ btab, float* __restrict__ btf) {
    int idx = blockIdx.x * 256 + threadIdx.x;    // over 12*22*22*64
    if (idx >= 12 * 22 * 22 * 64) return;
    int lane = idx & 63, rem = idx >> 6;
    int nb = rem % 22; rem /= 22;
    int rt = rem % 22; int head = rem / 22;
    int j = nb * 16 + (lane & 15);
    int ibase = rt * 16 + (lane >> 4) * 4;
    f32x4 out;
    #pragma unroll
    for (int r = 0; r < 4; r++) {
        int i = ibase + r;
        float v;
        if (j >= 344) v = -1e30f;
        else if (i >= 344 || i == 0 || j == 0) v = 0.f;
        else {
            int ti = i - 1, tj = j - 1;
            int ai = ti / 49, bi = (ti % 49) / 7, ci = ti % 7;
            int aj = tj / 49, bj = (tj % 49) / 7, cj = tj % 7;
            int id3 = (ai - aj + 6) * 20 + (bi - bj + 6) * 13 + (ci - cj + 6);
            v = btab[id3 * 12 + head];
        }
        out[r] = v;
    }
    *(f32x4*)&btf[(size_t)idx * 4] = out;
}

// ---------------- precompute shift-mask group ids: gid[64][352] uint8 ----------------
__global__ void gid_pre(unsigned char* __restrict__ gid) {
    int idx = blockIdx.x * 256 + threadIdx.x;
    if (idx >= 64 * 352) return;
    int w = idx / 352, n = idx % 352;
    unsigned char g = 0;
    if (n >= 1 && n < 344) {
        int t = n - 1;
        int a = t / 49, bb = (t % 49) / 7, cc = t % 7;
        int hw = w >> 3, ww = w & 7;
        int h = hw * 7 + bb, wd = ww * 7 + cc;
        int gs = (a < 4) ? 1 : 2;
        int gh = (h < 49) ? 0 : ((h < 53) ? 1 : 2);
        int gw = (wd < 49) ? 0 : ((wd < 53) ? 1 : 2);
        g = (unsigned char)(gs * 9 + gh * 3 + gw);
    }
    gid[idx] = g;
}

// ---------------- LN1 + roll(-3) + window partition + gt concat ----------------
__global__ __launch_bounds__(256) void ln1_window(
    const float* __restrict__ x, const float* __restrict__ gt,
    const float* __restrict__ g, const float* __restrict__ b,
    short* __restrict__ xc)
{
    int wid = threadIdx.x >> 6, lane = threadIdx.x & 63;
    int r = blockIdx.x * 4 + wid;
    int w = r / 344, n = r - w * 344;
    if (n == 0) {
        #pragma unroll
        for (int i = 0; i < 6; i++) {
            int c = lane + i * 64;
            xc[(size_t)r * 384 + c] = f2b(gt[(size_t)w * 384 + c]);
        }
        return;
    }
    int t = n - 1;
    int a = t / 49, rm = t - a * 49, bb = rm / 7, cc = rm - bb * 7;
    int hw = w >> 3, ww = w & 7;
    int s = (a < 4) ? a + 3 : a - 4;
    int h = hw * 7 + bb + 3; if (h >= 56) h -= 56;
    int wd = ww * 7 + cc + 3; if (wd >= 56) wd -= 56;
    const float* row = x + (size_t)((s * 56 + h) * 56 + wd) * 384;
    float v[6]; float sum = 0.f;
    #pragma unroll
    for (int i = 0; i < 6; i++) { v[i] = row[lane + i * 64]; sum += v[i]; }
    #pragma unroll
    for (int off = 32; off >= 1; off >>= 1) sum += __shfl_xor(sum, off);
    float mu = sum * (1.0f / 384.0f);
    float vs = 0.f;
    #pragma unroll
    for (int i = 0; i < 6; i++) { float d = v[i] - mu; vs += d * d; }
    #pragma unroll
    for (int off = 32; off >= 1; off >>= 1) vs += __shfl_xor(vs, off);
    float rstd = rsqrtf(vs * (1.0f / 384.0f) + 1e-5f);
    #pragma unroll
    for (int i = 0; i < 6; i++) {
        int c = lane + i * 64;
        float o = (v[i] - mu) * rstd * g[c] + b[c];
        xc[(size_t)r * 384 + c] = f2b(o);
    }
}

// ---------------- LN2 over fp32 x_new, token-major, out bf16 ----------------
__global__ __launch_bounds__(256) void ln2_kernel(
    const float* __restrict__ xn, const float* __restrict__ g,
    const float* __restrict__ b, short* __restrict__ out)
{
    int wid = threadIdx.x >> 6, lane = threadIdx.x & 63;
    int r = blockIdx.x * 4 + wid;
    const float* row = xn + (size_t)r * 384;
    float v[6]; float sum = 0.f;
    #pragma unroll
    for (int i = 0; i < 6; i++) { v[i] = row[lane + i * 64]; sum += v[i]; }
    #pragma unroll
    for (int off = 32; off >= 1; off >>= 1) sum += __shfl_xor(sum, off);
    float mu = sum * (1.0f / 384.0f);
    float vs = 0.f;
    #pragma unroll
    for (int i = 0; i < 6; i++) { float d = v[i] - mu; vs += d * d; }
    #pragma unroll
    for (int off = 32; off >= 1; off >>= 1) vs += __shfl_xor(vs, off);
    float rstd = rsqrtf(vs * (1.0f / 384.0f) + 1e-5f);
    #pragma unroll
    for (int i = 0; i < 6; i++) {
        int c = lane + i * 64;
        float o = (v[i] - mu) * rstd * g[c] + b[c];
        out[(size_t)r * 384 + c] = f2b(o);
    }
}

// ------- 128x128-tile bf16 MFMA GEMM, global_load_lds staging (m97 structure) -------
// LDS unpadded stride 32 (wave-uniform-base constraint of global_load_lds)
// QS: scale cols [0,384) by 32^-0.5 (Q pre-scaling for attention), EPI0 only
template<int EPI, bool QS>
__global__ __launch_bounds__(256) void gemm128(
    const short* __restrict__ A, const short* __restrict__ BT,
    const float* __restrict__ bias, void* __restrict__ Out,
    const void* __restrict__ P0, void* __restrict__ P1,
    int M, int N, int K)
{
    __shared__ short As[128 * 32];
    __shared__ short Bs[128 * 32];
    const int m0 = blockIdx.y * 128, n0 = blockIdx.x * 128;
    const int tid = threadIdx.x;
    const int wid = tid >> 6, lane = tid & 63;
    const int wm = wid >> 1, wn = wid & 1;
    const int l15 = lane & 15, quad = lane >> 4;
    const int lrow = lane >> 2, lcol = (lane & 3) * 8;

    f32x4 acc[4][4];
    #pragma unroll
    for (int i = 0; i < 4; i++)
        #pragma unroll
        for (int j = 0; j < 4; j++) acc[i][j] = (f32x4){0.f, 0.f, 0.f, 0.f};

    int arL = m0 + wid * 16 + lrow; if (arL >= M) arL = M - 1;
    int arH = m0 + 64 + wid * 16 + lrow; if (arH >= M) arH = M - 1;
    const short* AgL = A + (size_t)arL * K + lcol;
    const short* AgH = A + (size_t)arH * K + lcol;
    const short* BgL = BT + (size_t)(n0 + wid * 16 + lrow) * K + lcol;
    const short* BgH = BT + (size_t)(n0 + 64 + wid * 16 + lrow) * K + lcol;
    short* AsL = &As[wid * 512];
    short* AsH = &As[2048 + wid * 512];
    short* BsL = &Bs[wid * 512];
    short* BsH = &Bs[2048 + wid * 512];

    for (int ks = 0; ks < K; ks += 32) {
        gload16(AgL + ks, AsL);
        gload16(AgH + ks, AsH);
        gload16(BgL + ks, BsL);
        gload16(BgH + ks, BsH);
        __syncthreads();   // drains vmcnt: staging complete for all waves
        short8 af[4], bf[4];
        #pragma unroll
        for (int mt = 0; mt < 4; mt++)
            af[mt] = *(const short8*)&As[(wm * 64 + mt * 16 + l15) * 32 + quad * 8];
        #pragma unroll
        for (int nt = 0; nt < 4; nt++)
            bf[nt] = *(const short8*)&Bs[(wn * 64 + nt * 16 + l15) * 32 + quad * 8];
        #pragma unroll
        for (int mt = 0; mt < 4; mt++)
            #pragma unroll
            for (int nt = 0; nt < 4; nt++)
                acc[mt][nt] = __builtin_amdgcn_mfma_f32_16x16x32_bf16(af[mt], bf[nt],
                                                                      acc[mt][nt], 0, 0, 0);
        __syncthreads();   // all waves done reading before next overwrite
    }

    #pragma unroll
    for (int mt = 0; mt < 4; mt++) {
        #pragma unroll
        for (int nt = 0; nt < 4; nt++) {
            #pragma unroll
            for (int r = 0; r < 4; r++) {
                int row = m0 + wm * 64 + mt * 16 + quad * 4 + r;
                int col = n0 + wn * 64 + nt * 16 + l15;
                if (row >= M) continue;
                float v = acc[mt][nt][r] + bias[col];
                if (EPI == 0) {
                    if (QS && col < 384) v *= 0.17677669529663687f;
                    ((short*)Out)[(size_t)row * N + col] = f2b(v);
                } else if (EPI == 1) {
                    v = 0.5f * v * (1.0f + erff(v * 0.7071067811865476f));
                    ((short*)Out)[(size_t)row * N + col] = f2b(v);
                } else if (EPI == 2) {
                    int w = row / 344, n = row - w * 344;
                    if (n == 0) {
                        ((float*)P1)[(size_t)w * 384 + col] = v;
                    } else {
                        int t = n - 1;
                        int a = t / 49, rm = t - a * 49;
                        int bb = rm / 7, cc = rm - bb * 7;
                        int hw = w >> 3, ww = w & 7;
                        int s = (a < 4) ? a + 3 : a - 4;
                        int h = hw * 7 + bb + 3; if (h >= 56) h -= 56;
                        int wd = ww * 7 + cc + 3; if (wd >= 56) wd -= 56;
                        size_t td = (size_t)((s * 56 + h) * 56 + wd) * 384 + col;
                        ((float*)Out)[td] = v + ((const float*)P0)[td];
                    }
                } else {  // EPI 3
                    v += ((const float*)P0)[(size_t)row * N + col];
                    ((float*)Out)[(size_t)row * N + col] = v;
                }
            }
        }
    }
}

// ---------------- fused windowed attention, flash-style online softmax ----------------
// grid 1536: block -> (window, head, row-half). Q pre-scaled; bias enters QK^T as C-init.
__global__ __launch_bounds__(256) void attn_kernel(
    const short* __restrict__ qkv, const float* __restrict__ btf,
    const unsigned char* __restrict__ gid, short* __restrict__ attn_out)
{
    __shared__ short VT[32 * 360];        // V^T: [dd][key], stride 360
    __shared__ short Pbuf[4 * 16 * 40];   // per-wave P chunk
    __shared__ unsigned char Gs[352];
    const int blk = blockIdx.x;
    const int half = blk & 1, wh = blk >> 1;
    const int w = wh / 12, head = wh - w * 12;
    const int tid = threadIdx.x;
    const int wid = tid >> 6, lane = tid & 63;
    const int l15 = lane & 15, quad = lane >> 4;
    const size_t base = (size_t)w * 344 * 1152 + head * 32;

    for (int e = tid; e < 344 * 32; e += 256) {
        int key = e >> 5, dd = e & 31;
        VT[dd * 360 + key] = qkv[base + 768 + (size_t)key * 1152 + dd];
    }
    for (int e = tid; e < 16 * 32; e += 256) {
        int key = 344 + (e >> 5), dd = e & 31;
        VT[dd * 360 + key] = 0;
    }
    for (int e = tid; e < 352; e += 256) Gs[e] = gid[w * 352 + e];
    __syncthreads();

    const float* bh = btf + (size_t)head * (22 * 22 * 256);
    short* Pw = &Pbuf[wid * 640];

    for (int rtl = wid; rtl < 11; rtl += 4) {
        int rt = half * 11 + rtl;
        int mbase = rt * 16;
        int qr = mbase + l15; if (qr > 343) qr = 343;
        short8 af = *(const short8*)&qkv[base + (size_t)qr * 1152 + quad * 8];

        int rg[4]; bool ip[4];
        #pragma unroll
        for (int r = 0; r < 4; r++) {
            int i = mbase + quad * 4 + r;          // <= 351
            rg[r] = Gs[i];
            ip[r] = (i > 0);
        }

        f32x4 o0 = {0.f, 0.f, 0.f, 0.f}, o1 = {0.f, 0.f, 0.f, 0.f};
        float m[4] = {-1e30f, -1e30f, -1e30f, -1e30f};
        float l[4] = {0.f, 0.f, 0.f, 0.f};

        #pragma unroll
        for (int kk = 0; kk < 11; kk++) {
            int nb0 = kk * 2, nb1 = kk * 2 + 1;
            f32x4 b0 = *(const f32x4*)&bh[((size_t)(rt * 22 + nb0) * 64 + lane) * 4];
            f32x4 b1 = *(const f32x4*)&bh[((size_t)(rt * 22 + nb1) * 64 + lane) * 4];
            int kr0 = nb0 * 16 + l15; if (kr0 > 343) kr0 = 343;
            int kr1 = nb1 * 16 + l15; if (kr1 > 343) kr1 = 343;
            short8 k0 = *(const short8*)&qkv[base + 384 + (size_t)kr0 * 1152 + quad * 8];
            short8 k1 = *(const short8*)&qkv[base + 384 + (size_t)kr1 * 1152 + quad * 8];
            f32x4 s0 = __builtin_amdgcn_mfma_f32_16x16x32_bf16(af, k0, b0, 0, 0, 0);
            f32x4 s1 = __builtin_amdgcn_mfma_f32_16x16x32_bf16(af, k1, b1, 0, 0, 0);

            int j0 = nb0 * 16 + l15, j1 = nb1 * 16 + l15;
            int cg0 = Gs[j0], cg1 = Gs[j1];
            bool jp0 = (j0 > 0);                   // j1 >= 16 always > 0
            #pragma unroll
            for (int r = 0; r < 4; r++) {
                if (jp0 && ip[r] && rg[r] != cg0) s0[r] -= 100.0f;
                if (ip[r] && rg[r] != cg1) s1[r] -= 100.0f;
            }

            float t[4];
            #pragma unroll
            for (int r = 0; r < 4; r++) t[r] = fmaxf(s0[r], s1[r]);
            #pragma unroll
            for (int r = 0; r < 4; r++) {
                t[r] = fmaxf(t[r], __shfl_xor(t[r], 1));
                t[r] = fmaxf(t[r], __shfl_xor(t[r], 2));
                t[r] = fmaxf(t[r], __shfl_xor(t[r], 4));
                t[r] = fmaxf(t[r], __shfl_xor(t[r], 8));
            }
            #pragma unroll
            for (int r = 0; r < 4; r++) {
                float mn = fmaxf(m[r], t[r]);
                float a = __expf(m[r] - mn);
                m[r] = mn;
                float p0 = __expf(s0[r] - mn);
                float p1 = __expf(s1[r] - mn);
                l[r] = l[r] * a + p0 + p1;
                o0[r] *= a; o1[r] *= a;
                Pw[(quad * 4 + r) * 40 + l15] = f2b(p0);
                Pw[(quad * 4 + r) * 40 + 16 + l15] = f2b(p1);
            }
            short8 pa = *(const short8*)&Pw[l15 * 40 + quad * 8];
            short8 v0 = *(const short8*)&VT[l15 * 360 + kk * 32 + quad * 8];
            short8 v1 = *(const short8*)&VT[(16 + l15) * 360 + kk * 32 + quad * 8];
            o0 = __builtin_amdgcn_mfma_f32_16x16x32_bf16(pa, v0, o0, 0, 0, 0);
            o1 = __builtin_amdgcn_mfma_f32_16x16x32_bf16(pa, v1, o1, 0, 0, 0);
        }

        #pragma unroll
        for (int r = 0; r < 4; r++) {
            l[r] += __shfl_xor(l[r], 1);
            l[r] += __shfl_xor(l[r], 2);
            l[r] += __shfl_xor(l[r], 4);
            l[r] += __shfl_xor(l[r], 8);
        }
        #pragma unroll
        for (int r = 0; r < 4; r++) {
            int row = mbase + quad * 4 + r;
            if (row < 344) {
                float inv = 1.0f / l[r];
                size_t ob = ((size_t)w * 344 + row) * 384 + head * 32;
                attn_out[ob + l15] = f2b(o0[r] * inv);
                attn_out[ob + 16 + l15] = f2b(o1[r] * inv);
            }
        }
    }
}

extern "C" void kernel_launch(void* const* d_in, const int* in_sizes, int n_in,
                              void* d_out, int out_size, void* d_ws, size_t ws_size,
                              hipStream_t stream)
{
    const float* x      = (const float*)d_in[0];
    const float* gt     = (const float*)d_in[1];
    const float* n1g    = (const float*)d_in[2];
    const float* n1b    = (const float*)d_in[3];
    const float* qkv_w  = (const float*)d_in[4];
    const float* qkv_b  = (const float*)d_in[5];
    const float* btab   = (const float*)d_in[6];
    const float* proj_w = (const float*)d_in[7];
    const float* proj_b = (const float*)d_in[8];
    const float* n2g    = (const float*)d_in[9];
    const float* n2b    = (const float*)d_in[10];
    const float* fc1_w  = (const float*)d_in[11];
    const float* fc1_b  = (const float*)d_in[12];
    const float* fc2_w  = (const float*)d_in[13];
    const float* fc2_b  = (const float*)d_in[14];

    char* ws = (char*)d_ws;
    short* wt_qkv  = (short*)(ws + 0);          //  1152x384 bf16
    short* wt_proj = (short*)(ws + 884736);     //   384x384 bf16
    short* wt_fc1  = (short*)(ws + 1179648);    //  1536x384 bf16
    short* wt_fc2  = (short*)(ws + 2359296);    //   384x1536 bf16
    short* xc      = (short*)(ws + 3538944);    // 22016x384 bf16
    short* qkvb    = (short*)(ws + 20447232);   // 22016x1152 bf16
    short* attn_o  = xc;                        // reuse (xc dead after qkv GEMM)
    short* h1      = (short*)(ws + 3538944);    // 21952x1536 bf16 (reuse xc region)
    float* xnew    = (float*)(ws + 71172096);   // 21952x384 fp32
    float* btf     = (float*)(ws + 71172096);   // 12x22x22x64x4 fp32 (dead before xnew)
    unsigned char* gidb = (unsigned char*)(ws + 77119488);  // 64x352 u8
    short* xnorm   = (short*)(ws + 104890368);  // 21952x384 bf16

    float* outx  = (float*)d_out;
    float* outgt = outx + (size_t)21952 * 384;

    transpose_w<<<dim3((442368 + 255) / 256), 256, 0, stream>>>(qkv_w, wt_qkv, 384, 1152);
    transpose_w<<<dim3((147456 + 255) / 256), 256, 0, stream>>>(proj_w, wt_proj, 384, 384);
    transpose_w<<<dim3((589824 + 255) / 256), 256, 0, stream>>>(fc1_w, wt_fc1, 384, 1536);
    transpose_w<<<dim3((589824 + 255) / 256), 256, 0, stream>>>(fc2_w, wt_fc2, 1536, 384);

    bias_pre<<<dim3((12 * 22 * 22 * 64 + 255) / 256), 256, 0, stream>>>(btab, btf);
    gid_pre<<<dim3((64 * 352 + 255) / 256), 256, 0, stream>>>(gidb);

    ln1_window<<<dim3(5504), 256, 0, stream>>>(x, gt, n1g, n1b, xc);

    gemm128<0, true><<<dim3(9, 172), 256, 0, stream>>>(xc, wt_qkv, qkv_b, qkvb,
                                                       nullptr, nullptr, 22016, 1152, 384);

    attn_kernel<<<dim3(1536), 256, 0, stream>>>(qkvb, btf, gidb, attn_o);

    gemm128<2, false><<<dim3(3, 172), 256, 0, stream>>>(attn_o, wt_proj, proj_b, xnew,
                                                        x, outgt, 22016, 384, 384);

    ln2_kernel<<<dim3(5488), 256, 0, stream>>>(xnew, n2g, n2b, xnorm);

    gemm128<1, false><<<dim3(12, 172), 256, 0, stream>>>(xnorm, wt_fc1, fc1_b, h1,
                                                         nullptr, nullptr, 21952, 1536, 384);

    gemm128<3, false><<<dim3(3, 172), 256, 0, stream>>>(h1, wt_fc2, fc2_b, outx,
                                                        xnew, nullptr, 21952, 384, 1536);
}

// Round 7
// 458.535 us; speedup vs baseline: 1.2517x; 1.1278x over previous
//
#include <hip/hip_runtime.h>
#include <math.h>

typedef __attribute__((ext_vector_type(8))) short short8;
typedef __attribute__((ext_vector_type(4))) float f32x4;

__device__ __forceinline__ float b2f(short s) {
    unsigned u = ((unsigned)(unsigned short)s) << 16;
    return __builtin_bit_cast(float, u);
}
__device__ __forceinline__ short f2b(float f) {
    unsigned u = __builtin_bit_cast(unsigned, f);
    u += 0x7FFFu + ((u >> 16) & 1u);
    return (short)(u >> 16);
}
// async global->LDS, 16B per lane; lds base must be wave-uniform
__device__ __forceinline__ void gload16(const void* g, void* l) {
    __builtin_amdgcn_global_load_lds(
        (const __attribute__((address_space(1))) unsigned int*)g,
        (__attribute__((address_space(3))) unsigned int*)l, 16, 0, 0);
}

// ---------------- weight transpose + fp32->bf16: src (K x N fp32) -> dst (N x K bf16) ----
__global__ void transpose_w(const float* __restrict__ src, short* __restrict__ dst,
                            int K, int N) {
    int idx = blockIdx.x * 256 + threadIdx.x;
    if (idx < N * K) {
        int n = idx / K, k = idx - n * K;
        dst[idx] = f2b(src[(size_t)k * N + n]);
    }
}

// ------- precompute rel-pos bias in MFMA C-fragment layout: btf[12][22][22][64][4] -------
// value at (head, i=rt*16+(lane>>4)*4+r, j=nb*16+(lane&15)); j>=344 -> -1e30 (padding)
__global__ void bias_pre(const float* __restrict__ btab, float* __restrict__ btf) {
    int idx = blockIdx.x * 256 + threadIdx.x;    // over 12*22*22*64
    if (idx >= 12 * 22 * 22 * 64) return;
    int lane = idx & 63, rem = idx >> 6;
    int nb = rem % 22; rem /= 22;
    int rt = rem % 22; int head = rem / 22;
    int j = nb * 16 + (lane & 15);
    int ibase = rt * 16 + (lane >> 4) * 4;
    f32x4 out;
    #pragma unroll
    for (int r = 0; r < 4; r++) {
        int i = ibase + r;
        float v;
        if (j >= 344) v = -1e30f;
        else if (i >= 344 || i == 0 || j == 0) v = 0.f;
        else {
            int ti = i - 1, tj = j - 1;
            int ai = ti / 49, bi = (ti % 49) / 7, ci = ti % 7;
            int aj = tj / 49, bj = (tj % 49) / 7, cj = tj % 7;
            int id3 = (ai - aj + 6) * 20 + (bi - bj + 6) * 13 + (ci - cj + 6);
            v = btab[id3 * 12 + head];
        }
        out[r] = v;
    }
    *(f32x4*)&btf[(size_t)idx * 4] = out;
}

// ---------------- precompute shift-mask group ids: gid[64][352] uint8 ----------------
__global__ void gid_pre(unsigned char* __restrict__ gid) {
    int idx = blockIdx.x * 256 + threadIdx.x;
    if (idx >= 64 * 352) return;
    int w = idx / 352, n = idx % 352;
    unsigned char g = 0;
    if (n >= 1 && n < 344) {
        int t = n - 1;
        int a = t / 49, bb = (t % 49) / 7, cc = t % 7;
        int hw = w >> 3, ww = w & 7;
        int h = hw * 7 + bb, wd = ww * 7 + cc;
        int gs = (a < 4) ? 1 : 2;
        int gh = (h < 49) ? 0 : ((h < 53) ? 1 : 2);
        int gw = (wd < 49) ? 0 : ((wd < 53) ? 1 : 2);
        g = (unsigned char)(gs * 9 + gh * 3 + gw);
    }
    gid[idx] = g;
}

// ---------------- LN1 + roll(-3) + window partition + gt concat ----------------
__global__ __launch_bounds__(256) void ln1_window(
    const float* __restrict__ x, const float* __restrict__ gt,
    const float* __restrict__ g, const float* __restrict__ b,
    short* __restrict__ xc)
{
    int wid = threadIdx.x >> 6, lane = threadIdx.x & 63;
    int r = blockIdx.x * 4 + wid;
    int w = r / 344, n = r - w * 344;
    if (n == 0) {
        #pragma unroll
        for (int i = 0; i < 6; i++) {
            int c = lane + i * 64;
            xc[(size_t)r * 384 + c] = f2b(gt[(size_t)w * 384 + c]);
        }
        return;
    }
    int t = n - 1;
    int a = t / 49, rm = t - a * 49, bb = rm / 7, cc = rm - bb * 7;
    int hw = w >> 3, ww = w & 7;
    int s = (a < 4) ? a + 3 : a - 4;
    int h = hw * 7 + bb + 3; if (h >= 56) h -= 56;
    int wd = ww * 7 + cc + 3; if (wd >= 56) wd -= 56;
    const float* row = x + (size_t)((s * 56 + h) * 56 + wd) * 384;
    float v[6]; float sum = 0.f;
    #pragma unroll
    for (int i = 0; i < 6; i++) { v[i] = row[lane + i * 64]; sum += v[i]; }
    #pragma unroll
    for (int off = 32; off >= 1; off >>= 1) sum += __shfl_xor(sum, off);
    float mu = sum * (1.0f / 384.0f);
    float vs = 0.f;
    #pragma unroll
    for (int i = 0; i < 6; i++) { float d = v[i] - mu; vs += d * d; }
    #pragma unroll
    for (int off = 32; off >= 1; off >>= 1) vs += __shfl_xor(vs, off);
    float rstd = rsqrtf(vs * (1.0f / 384.0f) + 1e-5f);
    #pragma unroll
    for (int i = 0; i < 6; i++) {
        int c = lane + i * 64;
        float o = (v[i] - mu) * rstd * g[c] + b[c];
        xc[(size_t)r * 384 + c] = f2b(o);
    }
}

// ---------------- LN2 over fp32 x_new, token-major, out bf16 ----------------
__global__ __launch_bounds__(256) void ln2_kernel(
    const float* __restrict__ xn, const float* __restrict__ g,
    const float* __restrict__ b, short* __restrict__ out)
{
    int wid = threadIdx.x >> 6, lane = threadIdx.x & 63;
    int r = blockIdx.x * 4 + wid;
    const float* row = xn + (size_t)r * 384;
    float v[6]; float sum = 0.f;
    #pragma unroll
    for (int i = 0; i < 6; i++) { v[i] = row[lane + i * 64]; sum += v[i]; }
    #pragma unroll
    for (int off = 32; off >= 1; off >>= 1) sum += __shfl_xor(sum, off);
    float mu = sum * (1.0f / 384.0f);
    float vs = 0.f;
    #pragma unroll
    for (int i = 0; i < 6; i++) { float d = v[i] - mu; vs += d * d; }
    #pragma unroll
    for (int off = 32; off >= 1; off >>= 1) vs += __shfl_xor(vs, off);
    float rstd = rsqrtf(vs * (1.0f / 384.0f) + 1e-5f);
    #pragma unroll
    for (int i = 0; i < 6; i++) {
        int c = lane + i * 64;
        float o = (v[i] - mu) * rstd * g[c] + b[c];
        out[(size_t)r * 384 + c] = f2b(o);
    }
}

// ------- 128x128-tile bf16 MFMA GEMM, global_load_lds staging (m97 structure) -------
// LDS unpadded stride 32 (wave-uniform-base constraint of global_load_lds)
// QS: scale cols [0,384) by 32^-0.5 (Q pre-scaling for attention), EPI0 only
template<int EPI, bool QS>
__global__ __launch_bounds__(256, 4) void gemm128(
    const short* __restrict__ A, const short* __restrict__ BT,
    const float* __restrict__ bias, void* __restrict__ Out,
    const void* __restrict__ P0, void* __restrict__ P1,
    int M, int N, int K)
{
    __shared__ short As[128 * 32];
    __shared__ short Bs[128 * 32];
    const int m0 = blockIdx.y * 128, n0 = blockIdx.x * 128;
    const int tid = threadIdx.x;
    const int wid = tid >> 6, lane = tid & 63;
    const int wm = wid >> 1, wn = wid & 1;
    const int l15 = lane & 15, quad = lane >> 4;
    const int lrow = lane >> 2, lcol = (lane & 3) * 8;

    f32x4 acc[4][4];
    #pragma unroll
    for (int i = 0; i < 4; i++)
        #pragma unroll
        for (int j = 0; j < 4; j++) acc[i][j] = (f32x4){0.f, 0.f, 0.f, 0.f};

    int arL = m0 + wid * 16 + lrow; if (arL >= M) arL = M - 1;
    int arH = m0 + 64 + wid * 16 + lrow; if (arH >= M) arH = M - 1;
    const short* AgL = A + (size_t)arL * K + lcol;
    const short* AgH = A + (size_t)arH * K + lcol;
    const short* BgL = BT + (size_t)(n0 + wid * 16 + lrow) * K + lcol;
    const short* BgH = BT + (size_t)(n0 + 64 + wid * 16 + lrow) * K + lcol;
    short* AsL = &As[wid * 512];
    short* AsH = &As[2048 + wid * 512];
    short* BsL = &Bs[wid * 512];
    short* BsH = &Bs[2048 + wid * 512];

    for (int ks = 0; ks < K; ks += 32) {
        gload16(AgL + ks, AsL);
        gload16(AgH + ks, AsH);
        gload16(BgL + ks, BsL);
        gload16(BgH + ks, BsH);
        __syncthreads();   // drains vmcnt: staging complete for all waves
        short8 af[4], bf[4];
        #pragma unroll
        for (int mt = 0; mt < 4; mt++)
            af[mt] = *(const short8*)&As[(wm * 64 + mt * 16 + l15) * 32 + quad * 8];
        #pragma unroll
        for (int nt = 0; nt < 4; nt++)
            bf[nt] = *(const short8*)&Bs[(wn * 64 + nt * 16 + l15) * 32 + quad * 8];
        #pragma unroll
        for (int mt = 0; mt < 4; mt++)
            #pragma unroll
            for (int nt = 0; nt < 4; nt++)
                acc[mt][nt] = __builtin_amdgcn_mfma_f32_16x16x32_bf16(af[mt], bf[nt],
                                                                      acc[mt][nt], 0, 0, 0);
        __syncthreads();   // all waves done reading before next overwrite
    }

    #pragma unroll
    for (int mt = 0; mt < 4; mt++) {
        #pragma unroll
        for (int nt = 0; nt < 4; nt++) {
            #pragma unroll
            for (int r = 0; r < 4; r++) {
                int row = m0 + wm * 64 + mt * 16 + quad * 4 + r;
                int col = n0 + wn * 64 + nt * 16 + l15;
                if (row >= M) continue;
                float v = acc[mt][nt][r] + bias[col];
                if (EPI == 0) {
                    if (QS && col < 384) v *= 0.17677669529663687f;
                    ((short*)Out)[(size_t)row * N + col] = f2b(v);
                } else if (EPI == 1) {
                    v = 0.5f * v * (1.0f + erff(v * 0.7071067811865476f));
                    ((short*)Out)[(size_t)row * N + col] = f2b(v);
                } else if (EPI == 2) {
                    int w = row / 344, n = row - w * 344;
                    if (n == 0) {
                        ((float*)P1)[(size_t)w * 384 + col] = v;
                    } else {
                        int t = n - 1;
                        int a = t / 49, rm = t - a * 49;
                        int bb = rm / 7, cc = rm - bb * 7;
                        int hw = w >> 3, ww = w & 7;
                        int s = (a < 4) ? a + 3 : a - 4;
                        int h = hw * 7 + bb + 3; if (h >= 56) h -= 56;
                        int wd = ww * 7 + cc + 3; if (wd >= 56) wd -= 56;
                        size_t td = (size_t)((s * 56 + h) * 56 + wd) * 384 + col;
                        ((float*)Out)[td] = v + ((const float*)P0)[td];
                    }
                } else {  // EPI 3
                    v += ((const float*)P0)[(size_t)row * N + col];
                    ((float*)Out)[(size_t)row * N + col] = v;
                }
            }
        }
    }
}

// -------- fused windowed attention: K+V in LDS, no-max softmax (scores bounded) --------
// grid 1536: block -> (window, head, row-half). Q pre-scaled; bias enters QK^T as C-init.
__global__ __launch_bounds__(256) void attn_kernel(
    const short* __restrict__ qkv, const float* __restrict__ btf,
    const unsigned char* __restrict__ gid, short* __restrict__ attn_out)
{
    __shared__ short KT[352 * 40];        // K rows, stride 40 (80B, 16B-aligned)
    __shared__ short VT[32 * 360];        // V^T: [dd][key], stride 360
    __shared__ short Pbuf[4 * 16 * 40];   // per-wave P chunk
    __shared__ unsigned char Gs[352];
    const int blk = blockIdx.x;
    const int half = blk & 1, wh = blk >> 1;
    const int w = wh / 12, head = wh - w * 12;
    const int tid = threadIdx.x;
    const int wid = tid >> 6, lane = tid & 63;
    const int l15 = lane & 15, quad = lane >> 4;
    const size_t base = (size_t)w * 344 * 1152 + head * 32;

    // stage K rows (zero-pad rows 344..351)
    for (int c = tid; c < 352 * 4; c += 256) {
        int row = c >> 2, off = (c & 3) * 8;
        short8 v8 = (short8){0,0,0,0,0,0,0,0};
        if (row < 344) v8 = *(const short8*)&qkv[base + 384 + (size_t)row * 1152 + off];
        *(short8*)&KT[row * 40 + off] = v8;
    }
    // stage V transposed
    for (int e = tid; e < 344 * 32; e += 256) {
        int key = e >> 5, dd = e & 31;
        VT[dd * 360 + key] = qkv[base + 768 + (size_t)key * 1152 + dd];
    }
    for (int e = tid; e < 16 * 32; e += 256) {
        int key = 344 + (e >> 5), dd = e & 31;
        VT[dd * 360 + key] = 0;
    }
    for (int e = tid; e < 352; e += 256) Gs[e] = gid[w * 352 + e];
    __syncthreads();

    const float* bh = btf + (size_t)head * (22 * 22 * 256);
    short* Pw = &Pbuf[wid * 640];

    for (int rtl = wid; rtl < 11; rtl += 4) {
        int rt = half * 11 + rtl;
        int mbase = rt * 16;
        int qr = mbase + l15; if (qr > 343) qr = 343;
        short8 af = *(const short8*)&qkv[base + (size_t)qr * 1152 + quad * 8];

        int rg[4]; bool ip[4];
        #pragma unroll
        for (int r = 0; r < 4; r++) {
            int i = mbase + quad * 4 + r;          // <= 351
            rg[r] = Gs[i];
            ip[r] = (i > 0);
        }

        f32x4 o0 = {0.f, 0.f, 0.f, 0.f}, o1 = {0.f, 0.f, 0.f, 0.f};
        float l[4] = {0.f, 0.f, 0.f, 0.f};

        #pragma unroll
        for (int kk = 0; kk < 11; kk++) {
            int nb0 = kk * 2, nb1 = kk * 2 + 1;
            f32x4 b0 = *(const f32x4*)&bh[((size_t)(rt * 22 + nb0) * 64 + lane) * 4];
            f32x4 b1 = *(const f32x4*)&bh[((size_t)(rt * 22 + nb1) * 64 + lane) * 4];
            short8 k0 = *(const short8*)&KT[(nb0 * 16 + l15) * 40 + quad * 8];
            short8 k1 = *(const short8*)&KT[(nb1 * 16 + l15) * 40 + quad * 8];
            f32x4 s0 = __builtin_amdgcn_mfma_f32_16x16x32_bf16(af, k0, b0, 0, 0, 0);
            f32x4 s1 = __builtin_amdgcn_mfma_f32_16x16x32_bf16(af, k1, b1, 0, 0, 0);

            int j0 = nb0 * 16 + l15;
            int cg0 = Gs[j0], cg1 = Gs[j0 + 16];
            bool jp0 = (j0 > 0);                   // j1 >= 16 always > 0
            // no-max softmax: scores bounded (|qk|+bias few units; -100/-1e30 underflow to 0)
            #pragma unroll
            for (int r = 0; r < 4; r++) {
                float s0r = s0[r], s1r = s1[r];
                if (jp0 && ip[r] && rg[r] != cg0) s0r -= 100.0f;
                if (ip[r] && rg[r] != cg1) s1r -= 100.0f;
                float p0 = __expf(s0r);
                float p1 = __expf(s1r);
                l[r] += p0 + p1;
                Pw[(quad * 4 + r) * 40 + l15] = f2b(p0);
                Pw[(quad * 4 + r) * 40 + 16 + l15] = f2b(p1);
            }
            short8 pa = *(const short8*)&Pw[l15 * 40 + quad * 8];
            short8 v0 = *(const short8*)&VT[l15 * 360 + kk * 32 + quad * 8];
            short8 v1 = *(const short8*)&VT[(16 + l15) * 360 + kk * 32 + quad * 8];
            o0 = __builtin_amdgcn_mfma_f32_16x16x32_bf16(pa, v0, o0, 0, 0, 0);
            o1 = __builtin_amdgcn_mfma_f32_16x16x32_bf16(pa, v1, o1, 0, 0, 0);
        }

        #pragma unroll
        for (int r = 0; r < 4; r++) {
            l[r] += __shfl_xor(l[r], 1);
            l[r] += __shfl_xor(l[r], 2);
            l[r] += __shfl_xor(l[r], 4);
            l[r] += __shfl_xor(l[r], 8);
        }
        #pragma unroll
        for (int r = 0; r < 4; r++) {
            int row = mbase + quad * 4 + r;
            if (row < 344) {
                float inv = 1.0f / l[r];
                size_t ob = ((size_t)w * 344 + row) * 384 + head * 32;
                attn_out[ob + l15] = f2b(o0[r] * inv);
                attn_out[ob + 16 + l15] = f2b(o1[r] * inv);
            }
        }
    }
}

extern "C" void kernel_launch(void* const* d_in, const int* in_sizes, int n_in,
                              void* d_out, int out_size, void* d_ws, size_t ws_size,
                              hipStream_t stream)
{
    const float* x      = (const float*)d_in[0];
    const float* gt     = (const float*)d_in[1];
    const float* n1g    = (const float*)d_in[2];
    const float* n1b    = (const float*)d_in[3];
    const float* qkv_w  = (const float*)d_in[4];
    const float* qkv_b  = (const float*)d_in[5];
    const float* btab   = (const float*)d_in[6];
    const float* proj_w = (const float*)d_in[7];
    const float* proj_b = (const float*)d_in[8];
    const float* n2g    = (const float*)d_in[9];
    const float* n2b    = (const float*)d_in[10];
    const float* fc1_w  = (const float*)d_in[11];
    const float* fc1_b  = (const float*)d_in[12];
    const float* fc2_w  = (const float*)d_in[13];
    const float* fc2_b  = (const float*)d_in[14];

    char* ws = (char*)d_ws;
    short* wt_qkv  = (short*)(ws + 0);          //  1152x384 bf16
    short* wt_proj = (short*)(ws + 884736);     //   384x384 bf16
    short* wt_fc1  = (short*)(ws + 1179648);    //  1536x384 bf16
    short* wt_fc2  = (short*)(ws + 2359296);    //   384x1536 bf16
    short* xc      = (short*)(ws + 3538944);    // 22016x384 bf16
    short* qkvb    = (short*)(ws + 20447232);   // 22016x1152 bf16
    short* attn_o  = xc;                        // reuse (xc dead after qkv GEMM)
    short* h1      = (short*)(ws + 3538944);    // 21952x1536 bf16 (reuse xc region)
    float* xnew    = (float*)(ws + 71172096);   // 21952x384 fp32
    float* btf     = (float*)(ws + 71172096);   // 12x22x22x64x4 fp32 (dead before xnew)
    unsigned char* gidb = (unsigned char*)(ws + 77119488);  // 64x352 u8
    short* xnorm   = (short*)(ws + 104890368);  // 21952x384 bf16

    float* outx  = (float*)d_out;
    float* outgt = outx + (size_t)21952 * 384;

    transpose_w<<<dim3((442368 + 255) / 256), 256, 0, stream>>>(qkv_w, wt_qkv, 384, 1152);
    transpose_w<<<dim3((147456 + 255) / 256), 256, 0, stream>>>(proj_w, wt_proj, 384, 384);
    transpose_w<<<dim3((589824 + 255) / 256), 256, 0, stream>>>(fc1_w, wt_fc1, 384, 1536);
    transpose_w<<<dim3((589824 + 255) / 256), 256, 0, stream>>>(fc2_w, wt_fc2, 1536, 384);

    bias_pre<<<dim3((12 * 22 * 22 * 64 + 255) / 256), 256, 0, stream>>>(btab, btf);
    gid_pre<<<dim3((64 * 352 + 255) / 256), 256, 0, stream>>>(gidb);

    ln1_window<<<dim3(5504), 256, 0, stream>>>(x, gt, n1g, n1b, xc);

    gemm128<0, true><<<dim3(9, 172), 256, 0, stream>>>(xc, wt_qkv, qkv_b, qkvb,
                                                       nullptr, nullptr, 22016, 1152, 384);

    attn_kernel<<<dim3(1536), 256, 0, stream>>>(qkvb, btf, gidb, attn_o);

    gemm128<2, false><<<dim3(3, 172), 256, 0, stream>>>(attn_o, wt_proj, proj_b, xnew,
                                                        x, outgt, 22016, 384, 384);

    ln2_kernel<<<dim3(5488), 256, 0, stream>>>(xnew, n2g, n2b, xnorm);

    gemm128<1, false><<<dim3(12, 172), 256, 0, stream>>>(xnorm, wt_fc1, fc1_b, h1,
                                                         nullptr, nullptr, 21952, 1536, 384);

    gemm128<3, false><<<dim3(3, 172), 256, 0, stream>>>(h1, wt_fc2, fc2_b, outx,
                                                        xnew, nullptr, 21952, 384, 1536);
}

// Round 8
// 449.487 us; speedup vs baseline: 1.2769x; 1.0201x over previous
//
#include <hip/hip_runtime.h>
#include <math.h>

typedef __attribute__((ext_vector_type(8))) short short8;
typedef __attribute__((ext_vector_type(4))) float f32x4;

__device__ __forceinline__ float b2f(short s) {
    unsigned u = ((unsigned)(unsigned short)s) << 16;
    return __builtin_bit_cast(float, u);
}
__device__ __forceinline__ short f2b(float f) {
    unsigned u = __builtin_bit_cast(unsigned, f);
    u += 0x7FFFu + ((u >> 16) & 1u);
    return (short)(u >> 16);
}
// async global->LDS, 16B per lane; lds base must be wave-uniform
__device__ __forceinline__ void gload16(const void* g, void* l) {
    __builtin_amdgcn_global_load_lds(
        (const __attribute__((address_space(1))) unsigned int*)g,
        (__attribute__((address_space(3))) unsigned int*)l, 16, 0, 0);
}

// ---------------- weight transpose + fp32->bf16: src (K x N fp32) -> dst (N x K bf16) ----
__global__ void transpose_w(const float* __restrict__ src, short* __restrict__ dst,
                            int K, int N) {
    int idx = blockIdx.x * 256 + threadIdx.x;
    if (idx < N * K) {
        int n = idx / K, k = idx - n * K;
        dst[idx] = f2b(src[(size_t)k * N + n]);
    }
}

// ------- precompute rel-pos bias in MFMA C-fragment layout: btf[12][22][22][64][4] -------
__global__ void bias_pre(const float* __restrict__ btab, float* __restrict__ btf) {
    int idx = blockIdx.x * 256 + threadIdx.x;    // over 12*22*22*64
    if (idx >= 12 * 22 * 22 * 64) return;
    int lane = idx & 63, rem = idx >> 6;
    int nb = rem % 22; rem /= 22;
    int rt = rem % 22; int head = rem / 22;
    int j = nb * 16 + (lane & 15);
    int ibase = rt * 16 + (lane >> 4) * 4;
    f32x4 out;
    #pragma unroll
    for (int r = 0; r < 4; r++) {
        int i = ibase + r;
        float v;
        if (j >= 344) v = -1e30f;
        else if (i >= 344 || i == 0 || j == 0) v = 0.f;
        else {
            int ti = i - 1, tj = j - 1;
            int ai = ti / 49, bi = (ti % 49) / 7, ci = ti % 7;
            int aj = tj / 49, bj = (tj % 49) / 7, cj = tj % 7;
            int id3 = (ai - aj + 6) * 20 + (bi - bj + 6) * 13 + (ci - cj + 6);
            v = btab[id3 * 12 + head];
        }
        out[r] = v;
    }
    *(f32x4*)&btf[(size_t)idx * 4] = out;
}

// ---------------- precompute shift-mask group ids: gid[64][352] uint8 ----------------
__global__ void gid_pre(unsigned char* __restrict__ gid) {
    int idx = blockIdx.x * 256 + threadIdx.x;
    if (idx >= 64 * 352) return;
    int w = idx / 352, n = idx % 352;
    unsigned char g = 0;
    if (n >= 1 && n < 344) {
        int t = n - 1;
        int a = t / 49, bb = (t % 49) / 7, cc = t % 7;
        int hw = w >> 3, ww = w & 7;
        int h = hw * 7 + bb, wd = ww * 7 + cc;
        int gs = (a < 4) ? 1 : 2;
        int gh = (h < 49) ? 0 : ((h < 53) ? 1 : 2);
        int gw = (wd < 49) ? 0 : ((wd < 53) ? 1 : 2);
        g = (unsigned char)(gs * 9 + gh * 3 + gw);
    }
    gid[idx] = g;
}

// ---------------- LN1 + roll(-3) + window partition + gt concat ----------------
__global__ __launch_bounds__(256) void ln1_window(
    const float* __restrict__ x, const float* __restrict__ gt,
    const float* __restrict__ g, const float* __restrict__ b,
    short* __restrict__ xc)
{
    int wid = threadIdx.x >> 6, lane = threadIdx.x & 63;
    int r = blockIdx.x * 4 + wid;
    int w = r / 344, n = r - w * 344;
    if (n == 0) {
        #pragma unroll
        for (int i = 0; i < 6; i++) {
            int c = lane + i * 64;
            xc[(size_t)r * 384 + c] = f2b(gt[(size_t)w * 384 + c]);
        }
        return;
    }
    int t = n - 1;
    int a = t / 49, rm = t - a * 49, bb = rm / 7, cc = rm - bb * 7;
    int hw = w >> 3, ww = w & 7;
    int s = (a < 4) ? a + 3 : a - 4;
    int h = hw * 7 + bb + 3; if (h >= 56) h -= 56;
    int wd = ww * 7 + cc + 3; if (wd >= 56) wd -= 56;
    const float* row = x + (size_t)((s * 56 + h) * 56 + wd) * 384;
    float v[6]; float sum = 0.f;
    #pragma unroll
    for (int i = 0; i < 6; i++) { v[i] = row[lane + i * 64]; sum += v[i]; }
    #pragma unroll
    for (int off = 32; off >= 1; off >>= 1) sum += __shfl_xor(sum, off);
    float mu = sum * (1.0f / 384.0f);
    float vs = 0.f;
    #pragma unroll
    for (int i = 0; i < 6; i++) { float d = v[i] - mu; vs += d * d; }
    #pragma unroll
    for (int off = 32; off >= 1; off >>= 1) vs += __shfl_xor(vs, off);
    float rstd = rsqrtf(vs * (1.0f / 384.0f) + 1e-5f);
    #pragma unroll
    for (int i = 0; i < 6; i++) {
        int c = lane + i * 64;
        float o = (v[i] - mu) * rstd * g[c] + b[c];
        xc[(size_t)r * 384 + c] = f2b(o);
    }
}

// ---------------- LN2 over fp32 x_new, token-major, out bf16 ----------------
__global__ __launch_bounds__(256) void ln2_kernel(
    const float* __restrict__ xn, const float* __restrict__ g,
    const float* __restrict__ b, short* __restrict__ out)
{
    int wid = threadIdx.x >> 6, lane = threadIdx.x & 63;
    int r = blockIdx.x * 4 + wid;
    const float* row = xn + (size_t)r * 384;
    float v[6]; float sum = 0.f;
    #pragma unroll
    for (int i = 0; i < 6; i++) { v[i] = row[lane + i * 64]; sum += v[i]; }
    #pragma unroll
    for (int off = 32; off >= 1; off >>= 1) sum += __shfl_xor(sum, off);
    float mu = sum * (1.0f / 384.0f);
    float vs = 0.f;
    #pragma unroll
    for (int i = 0; i < 6; i++) { float d = v[i] - mu; vs += d * d; }
    #pragma unroll
    for (int off = 32; off >= 1; off >>= 1) vs += __shfl_xor(vs, off);
    float rstd = rsqrtf(vs * (1.0f / 384.0f) + 1e-5f);
    #pragma unroll
    for (int i = 0; i < 6; i++) {
        int c = lane + i * 64;
        float o = (v[i] - mu) * rstd * g[c] + b[c];
        out[(size_t)r * 384 + c] = f2b(o);
    }
}

// ------- 128x128-tile bf16 MFMA GEMM, BK=64, global_load_lds + XOR-swizzled LDS -------
// LDS row = 64 halves = 8 chunks of 16B; chunk c of row r lives at slot c^(r&7).
// Staging picks global chunk c = cs ^ (r&7) for LDS slot cs so dest = base + lane*16.
// QS: scale cols [0,384) by 32^-0.5 (Q pre-scaling for attention), EPI0 only
template<int EPI, bool QS>
__global__ __launch_bounds__(256, 4) void gemm128(
    const short* __restrict__ A, const short* __restrict__ BT,
    const float* __restrict__ bias, void* __restrict__ Out,
    const void* __restrict__ P0, void* __restrict__ P1,
    int M, int N, int K)
{
    __shared__ short As[128 * 64];
    __shared__ short Bs[128 * 64];
    const int m0 = blockIdx.y * 128, n0 = blockIdx.x * 128;
    const int tid = threadIdx.x;
    const int wid = tid >> 6, lane = tid & 63;
    const int wm = wid >> 1, wn = wid & 1;
    const int l15 = lane & 15, quad = lane >> 4;

    f32x4 acc[4][4];
    #pragma unroll
    for (int i = 0; i < 4; i++)
        #pragma unroll
        for (int j = 0; j < 4; j++) acc[i][j] = (f32x4){0.f, 0.f, 0.f, 0.f};

    // staging geometry: thread -> (row trow + j*32, slot cs), global chunk c
    const int trow = tid >> 3;                 // 0..31
    const int cs = tid & 7;
    const int gc = cs ^ (trow & 7);            // global 16B-chunk index
    const short* Ag[4]; const short* Bg[4];
    #pragma unroll
    for (int j = 0; j < 4; j++) {
        int ar = m0 + j * 32 + trow; if (ar >= M) ar = M - 1;
        Ag[j] = A + (size_t)ar * K + gc * 8;
        Bg[j] = BT + (size_t)(n0 + j * 32 + trow) * K + gc * 8;
    }
    // per-wave uniform LDS bases (lane*16B spans 8 rows x 8 slots)
    short* AsW[4]; short* BsW[4];
    #pragma unroll
    for (int j = 0; j < 4; j++) {
        AsW[j] = &As[(j * 32 + wid * 8) * 64];
        BsW[j] = &Bs[(j * 32 + wid * 8) * 64];
    }
    // fragment read offsets (halves): row*64 + ((ko*4+quad)^(row&7))*8
    int arow[4], brow[4];
    #pragma unroll
    for (int mt = 0; mt < 4; mt++) arow[mt] = wm * 64 + mt * 16 + l15;
    #pragma unroll
    for (int nt = 0; nt < 4; nt++) brow[nt] = wn * 64 + nt * 16 + l15;

    for (int ks = 0; ks < K; ks += 64) {
        #pragma unroll
        for (int j = 0; j < 4; j++) gload16(Ag[j] + ks, AsW[j]);
        #pragma unroll
        for (int j = 0; j < 4; j++) gload16(Bg[j] + ks, BsW[j]);
        __syncthreads();   // drains vmcnt: staging complete for all waves
        #pragma unroll
        for (int ko = 0; ko < 2; ko++) {
            short8 af[4], bf[4];
            #pragma unroll
            for (int mt = 0; mt < 4; mt++)
                af[mt] = *(const short8*)&As[arow[mt] * 64
                         + (((ko * 4 + quad) ^ (l15 & 7)) * 8)];
            #pragma unroll
            for (int nt = 0; nt < 4; nt++)
                bf[nt] = *(const short8*)&Bs[brow[nt] * 64
                         + (((ko * 4 + quad) ^ (l15 & 7)) * 8)];
            #pragma unroll
            for (int mt = 0; mt < 4; mt++)
                #pragma unroll
                for (int nt = 0; nt < 4; nt++)
                    acc[mt][nt] = __builtin_amdgcn_mfma_f32_16x16x32_bf16(
                        af[mt], bf[nt], acc[mt][nt], 0, 0, 0);
        }
        __syncthreads();   // all waves done reading before next overwrite
    }

    #pragma unroll
    for (int mt = 0; mt < 4; mt++) {
        #pragma unroll
        for (int nt = 0; nt < 4; nt++) {
            #pragma unroll
            for (int r = 0; r < 4; r++) {
                int row = m0 + wm * 64 + mt * 16 + quad * 4 + r;
                int col = n0 + wn * 64 + nt * 16 + l15;
                if (row >= M) continue;
                float v = acc[mt][nt][r] + bias[col];
                if (EPI == 0) {
                    if (QS && col < 384) v *= 0.17677669529663687f;
                    ((short*)Out)[(size_t)row * N + col] = f2b(v);
                } else if (EPI == 1) {
                    v = 0.5f * v * (1.0f + erff(v * 0.7071067811865476f));
                    ((short*)Out)[(size_t)row * N + col] = f2b(v);
                } else if (EPI == 2) {
                    int w = row / 344, n = row - w * 344;
                    if (n == 0) {
                        ((float*)P1)[(size_t)w * 384 + col] = v;
                    } else {
                        int t = n - 1;
                        int a = t / 49, rm = t - a * 49;
                        int bb = rm / 7, cc = rm - bb * 7;
                        int hw = w >> 3, ww = w & 7;
                        int s = (a < 4) ? a + 3 : a - 4;
                        int h = hw * 7 + bb + 3; if (h >= 56) h -= 56;
                        int wd = ww * 7 + cc + 3; if (wd >= 56) wd -= 56;
                        size_t td = (size_t)((s * 56 + h) * 56 + wd) * 384 + col;
                        ((float*)Out)[td] = v + ((const float*)P0)[td];
                    }
                } else {  // EPI 3
                    v += ((const float*)P0)[(size_t)row * N + col];
                    ((float*)Out)[(size_t)row * N + col] = v;
                }
            }
        }
    }
}

// -------- fused windowed attention: K+V in LDS, no-max softmax (scores bounded) --------
__global__ __launch_bounds__(256) void attn_kernel(
    const short* __restrict__ qkv, const float* __restrict__ btf,
    const unsigned char* __restrict__ gid, short* __restrict__ attn_out)
{
    __shared__ short KT[352 * 40];        // K rows, stride 40 (80B, 16B-aligned)
    __shared__ short VT[32 * 360];        // V^T: [dd][key], stride 360
    __shared__ short Pbuf[4 * 16 * 40];   // per-wave P chunk
    __shared__ unsigned char Gs[352];
    const int blk = blockIdx.x;
    const int half = blk & 1, wh = blk >> 1;
    const int w = wh / 12, head = wh - w * 12;
    const int tid = threadIdx.x;
    const int wid = tid >> 6, lane = tid & 63;
    const int l15 = lane & 15, quad = lane >> 4;
    const size_t base = (size_t)w * 344 * 1152 + head * 32;

    for (int c = tid; c < 352 * 4; c += 256) {
        int row = c >> 2, off = (c & 3) * 8;
        short8 v8 = (short8){0,0,0,0,0,0,0,0};
        if (row < 344) v8 = *(const short8*)&qkv[base + 384 + (size_t)row * 1152 + off];
        *(short8*)&KT[row * 40 + off] = v8;
    }
    for (int e = tid; e < 344 * 32; e += 256) {
        int key = e >> 5, dd = e & 31;
        VT[dd * 360 + key] = qkv[base + 768 + (size_t)key * 1152 + dd];
    }
    for (int e = tid; e < 16 * 32; e += 256) {
        int key = 344 + (e >> 5), dd = e & 31;
        VT[dd * 360 + key] = 0;
    }
    for (int e = tid; e < 352; e += 256) Gs[e] = gid[w * 352 + e];
    __syncthreads();

    const float* bh = btf + (size_t)head * (22 * 22 * 256);
    short* Pw = &Pbuf[wid * 640];

    for (int rtl = wid; rtl < 11; rtl += 4) {
        int rt = half * 11 + rtl;
        int mbase = rt * 16;
        int qr = mbase + l15; if (qr > 343) qr = 343;
        short8 af = *(const short8*)&qkv[base + (size_t)qr * 1152 + quad * 8];

        int rg[4]; bool ip[4];
        #pragma unroll
        for (int r = 0; r < 4; r++) {
            int i = mbase + quad * 4 + r;          // <= 351
            rg[r] = Gs[i];
            ip[r] = (i > 0);
        }

        f32x4 o0 = {0.f, 0.f, 0.f, 0.f}, o1 = {0.f, 0.f, 0.f, 0.f};
        float l[4] = {0.f, 0.f, 0.f, 0.f};

        #pragma unroll
        for (int kk = 0; kk < 11; kk++) {
            int nb0 = kk * 2, nb1 = kk * 2 + 1;
            f32x4 b0 = *(const f32x4*)&bh[((size_t)(rt * 22 + nb0) * 64 + lane) * 4];
            f32x4 b1 = *(const f32x4*)&bh[((size_t)(rt * 22 + nb1) * 64 + lane) * 4];
            short8 k0 = *(const short8*)&KT[(nb0 * 16 + l15) * 40 + quad * 8];
            short8 k1 = *(const short8*)&KT[(nb1 * 16 + l15) * 40 + quad * 8];
            f32x4 s0 = __builtin_amdgcn_mfma_f32_16x16x32_bf16(af, k0, b0, 0, 0, 0);
            f32x4 s1 = __builtin_amdgcn_mfma_f32_16x16x32_bf16(af, k1, b1, 0, 0, 0);

            int j0 = nb0 * 16 + l15;
            int cg0 = Gs[j0], cg1 = Gs[j0 + 16];
            bool jp0 = (j0 > 0);
            #pragma unroll
            for (int r = 0; r < 4; r++) {
                float s0r = s0[r], s1r = s1[r];
                if (jp0 && ip[r] && rg[r] != cg0) s0r -= 100.0f;
                if (ip[r] && rg[r] != cg1) s1r -= 100.0f;
                float p0 = __expf(s0r);
                float p1 = __expf(s1r);
                l[r] += p0 + p1;
                Pw[(quad * 4 + r) * 40 + l15] = f2b(p0);
                Pw[(quad * 4 + r) * 40 + 16 + l15] = f2b(p1);
            }
            short8 pa = *(const short8*)&Pw[l15 * 40 + quad * 8];
            short8 v0 = *(const short8*)&VT[l15 * 360 + kk * 32 + quad * 8];
            short8 v1 = *(const short8*)&VT[(16 + l15) * 360 + kk * 32 + quad * 8];
            o0 = __builtin_amdgcn_mfma_f32_16x16x32_bf16(pa, v0, o0, 0, 0, 0);
            o1 = __builtin_amdgcn_mfma_f32_16x16x32_bf16(pa, v1, o1, 0, 0, 0);
        }

        #pragma unroll
        for (int r = 0; r < 4; r++) {
            l[r] += __shfl_xor(l[r], 1);
            l[r] += __shfl_xor(l[r], 2);
            l[r] += __shfl_xor(l[r], 4);
            l[r] += __shfl_xor(l[r], 8);
        }
        #pragma unroll
        for (int r = 0; r < 4; r++) {
            int row = mbase + quad * 4 + r;
            if (row < 344) {
                float inv = 1.0f / l[r];
                size_t ob = ((size_t)w * 344 + row) * 384 + head * 32;
                attn_out[ob + l15] = f2b(o0[r] * inv);
                attn_out[ob + 16 + l15] = f2b(o1[r] * inv);
            }
        }
    }
}

extern "C" void kernel_launch(void* const* d_in, const int* in_sizes, int n_in,
                              void* d_out, int out_size, void* d_ws, size_t ws_size,
                              hipStream_t stream)
{
    const float* x      = (const float*)d_in[0];
    const float* gt     = (const float*)d_in[1];
    const float* n1g    = (const float*)d_in[2];
    const float* n1b    = (const float*)d_in[3];
    const float* qkv_w  = (const float*)d_in[4];
    const float* qkv_b  = (const float*)d_in[5];
    const float* btab   = (const float*)d_in[6];
    const float* proj_w = (const float*)d_in[7];
    const float* proj_b = (const float*)d_in[8];
    const float* n2g    = (const float*)d_in[9];
    const float* n2b    = (const float*)d_in[10];
    const float* fc1_w  = (const float*)d_in[11];
    const float* fc1_b  = (const float*)d_in[12];
    const float* fc2_w  = (const float*)d_in[13];
    const float* fc2_b  = (const float*)d_in[14];

    char* ws = (char*)d_ws;
    short* wt_qkv  = (short*)(ws + 0);          //  1152x384 bf16
    short* wt_proj = (short*)(ws + 884736);     //   384x384 bf16
    short* wt_fc1  = (short*)(ws + 1179648);    //  1536x384 bf16
    short* wt_fc2  = (short*)(ws + 2359296);    //   384x1536 bf16
    short* xc      = (short*)(ws + 3538944);    // 22016x384 bf16
    short* qkvb    = (short*)(ws + 20447232);   // 22016x1152 bf16
    short* attn_o  = xc;                        // reuse (xc dead after qkv GEMM)
    short* h1      = (short*)(ws + 3538944);    // 21952x1536 bf16 (reuse xc region)
    float* xnew    = (float*)(ws + 71172096);   // 21952x384 fp32
    float* btf     = (float*)(ws + 71172096);   // 12x22x22x64x4 fp32 (dead before xnew)
    unsigned char* gidb = (unsigned char*)(ws + 77119488);  // 64x352 u8
    short* xnorm   = (short*)(ws + 104890368);  // 21952x384 bf16

    float* outx  = (float*)d_out;
    float* outgt = outx + (size_t)21952 * 384;

    transpose_w<<<dim3((442368 + 255) / 256), 256, 0, stream>>>(qkv_w, wt_qkv, 384, 1152);
    transpose_w<<<dim3((147456 + 255) / 256), 256, 0, stream>>>(proj_w, wt_proj, 384, 384);
    transpose_w<<<dim3((589824 + 255) / 256), 256, 0, stream>>>(fc1_w, wt_fc1, 384, 1536);
    transpose_w<<<dim3((589824 + 255) / 256), 256, 0, stream>>>(fc2_w, wt_fc2, 1536, 384);

    bias_pre<<<dim3((12 * 22 * 22 * 64 + 255) / 256), 256, 0, stream>>>(btab, btf);
    gid_pre<<<dim3((64 * 352 + 255) / 256), 256, 0, stream>>>(gidb);

    ln1_window<<<dim3(5504), 256, 0, stream>>>(x, gt, n1g, n1b, xc);

    gemm128<0, true><<<dim3(9, 172), 256, 0, stream>>>(xc, wt_qkv, qkv_b, qkvb,
                                                       nullptr, nullptr, 22016, 1152, 384);

    attn_kernel<<<dim3(1536), 256, 0, stream>>>(qkvb, btf, gidb, attn_o);

    gemm128<2, false><<<dim3(3, 172), 256, 0, stream>>>(attn_o, wt_proj, proj_b, xnew,
                                                        x, outgt, 22016, 384, 384);

    ln2_kernel<<<dim3(5488), 256, 0, stream>>>(xnew, n2g, n2b, xnorm);

    gemm128<1, false><<<dim3(12, 172), 256, 0, stream>>>(xnorm, wt_fc1, fc1_b, h1,
                                                         nullptr, nullptr, 21952, 1536, 384);

    gemm128<3, false><<<dim3(3, 172), 256, 0, stream>>>(h1, wt_fc2, fc2_b, outx,
                                                        xnew, nullptr, 21952, 384, 1536);
}